// Round 2
// baseline (1506.552 us; speedup 1.0000x reference)
//
#include <hip/hip_runtime.h>

#define NN 100000
#define FIN 128
#define HD 32
#define EE 3200000

// ---------------- dtype detect: edge_index int32 vs int64 ----------------
// If stored as int64 (little-endian, values < 2^31), every odd 32-bit word is 0.
// If int32, odd words are random node ids in [0,100000) -> P(all 256 zero) ~ 0.
__global__ void detect_kernel(const unsigned int* __restrict__ ei32, int* __restrict__ flag) {
    int t = threadIdx.x;  // 0..63, single wave
    unsigned v = 0;
#pragma unroll
    for (int r = 0; r < 4; r++) v |= ei32[2 * (t + 64 * r) + 1];
    unsigned long long nz = __ballot(v != 0u);
    if (t == 0) *flag = (nz == 0ULL) ? 1 : 0;  // 1 => int64
}

__device__ __forceinline__ int load_idx(const int* ei, long long pos, int is64) {
    if (is64) return (int)((const long long*)ei)[pos];
    return ei[pos];
}

// ---------------- degree (with self-loop weight 1) ----------------
__global__ void deg_init_kernel(float* __restrict__ deg) {
    int i = blockIdx.x * blockDim.x + threadIdx.x;
    if (i < NN) deg[i] = 1.0f;  // self-loop contributes 1
}

__global__ void deg_accum_kernel(const int* __restrict__ ei, const float* __restrict__ wt,
                                 float* __restrict__ deg, const int* __restrict__ flag) {
    int e = blockIdx.x * blockDim.x + threadIdx.x;
    if (e >= EE) return;
    int is64 = *flag;
    int col = load_idx(ei, (long long)EE + e, is64);
    atomicAdd(deg + col, wt[e]);
}

__global__ void dinv_kernel(const float* __restrict__ deg, float* __restrict__ dinv) {
    int i = blockIdx.x * blockDim.x + threadIdx.x;
    if (i < NN) {
        float d = deg[i];
        dinv[i] = d > 0.f ? rsqrtf(d) : 0.f;
    }
}

// ---------------- xw = x @ [Wc_z | Wc_r | Wc_h]  (f32, LDS-tiled) ----------------
// Tile: 128 rows x 96 cols, K=128. 256 threads: tx=0..31 (cols tx,tx+32,tx+64),
// ty=0..7 (rows ty*16..ty*16+15). Full B (128x96) in LDS; A staged 8 k-slices.
__global__ __launch_bounds__(256) void gemm_xw_kernel(
        const float* __restrict__ x,
        const float* __restrict__ Wz, const float* __restrict__ Wr, const float* __restrict__ Wh,
        float* __restrict__ xw) {
    __shared__ float Bs[128 * 96];   // Bs[k*96 + c], k is GLOBAL k (0..127)
    __shared__ float AsT[8 * 128];   // AsT[kk*128 + row], kk is local (0..7)
    int tid = threadIdx.x;
    int tx = tid & 31, ty = tid >> 5;
    int rowBase = blockIdx.x * 128;

    for (int e = tid; e < 4096; e += 256) { int k = e >> 5, c = e & 31; Bs[k * 96 + c]      = Wz[e]; }
    for (int e = tid; e < 4096; e += 256) { int k = e >> 5, c = e & 31; Bs[k * 96 + 32 + c] = Wr[e]; }
    for (int e = tid; e < 4096; e += 256) { int k = e >> 5, c = e & 31; Bs[k * 96 + 64 + c] = Wh[e]; }

    float acc0[16], acc1[16], acc2[16];
#pragma unroll
    for (int r = 0; r < 16; r++) { acc0[r] = 0.f; acc1[r] = 0.f; acc2[r] = 0.f; }

    int lr = tid >> 1;             // 0..127: row within tile this thread loads
    int lc = (tid & 1) * 4;        // col offset 0 or 4 within k-chunk
    for (int k0 = 0; k0 < 128; k0 += 8) {
        __syncthreads();
        int gr = rowBase + lr;
        float4 a4 = make_float4(0.f, 0.f, 0.f, 0.f);
        if (gr < NN) a4 = *(const float4*)(x + (long long)gr * FIN + k0 + lc);
        AsT[(lc + 0) * 128 + lr] = a4.x;
        AsT[(lc + 1) * 128 + lr] = a4.y;
        AsT[(lc + 2) * 128 + lr] = a4.z;
        AsT[(lc + 3) * 128 + lr] = a4.w;
        __syncthreads();
#pragma unroll
        for (int kk = 0; kk < 8; kk++) {
            // NOTE: Bs is indexed by GLOBAL k = k0+kk (round-1 bug: used kk alone,
            // which reused weight rows 0..7 for every chunk -> absmax 0.094)
            float b0 = Bs[(k0 + kk) * 96 + tx];
            float b1 = Bs[(k0 + kk) * 96 + 32 + tx];
            float b2 = Bs[(k0 + kk) * 96 + 64 + tx];
            const float4* ap = (const float4*)(AsT + kk * 128 + ty * 16);
            float4 a0 = ap[0], a1 = ap[1], a2 = ap[2], a3 = ap[3];
            float av[16] = {a0.x,a0.y,a0.z,a0.w, a1.x,a1.y,a1.z,a1.w,
                            a2.x,a2.y,a2.z,a2.w, a3.x,a3.y,a3.z,a3.w};
#pragma unroll
            for (int r = 0; r < 16; r++) {
                acc0[r] = fmaf(av[r], b0, acc0[r]);
                acc1[r] = fmaf(av[r], b1, acc1[r]);
                acc2[r] = fmaf(av[r], b2, acc2[r]);
            }
        }
    }
#pragma unroll
    for (int r = 0; r < 16; r++) {
        int gr = rowBase + ty * 16 + r;
        if (gr < NN) {
            float* o = xw + (long long)gr * 96;
            o[tx] = acc0[r]; o[tx + 32] = acc1[r]; o[tx + 64] = acc2[r];
        }
    }
}

// ---------------- edge scatter: agg[col] += norm * xw[row] ----------------
// One edge per 32-lane group; 3 features per lane.
__global__ __launch_bounds__(256) void scatter_kernel(
        const int* __restrict__ ei, const float* __restrict__ wt,
        const float* __restrict__ dinv, const float* __restrict__ xw,
        float* __restrict__ agg, const int* __restrict__ flag) {
    long long gid = (long long)blockIdx.x * blockDim.x + threadIdx.x;
    int e = (int)(gid >> 5);
    if (e >= EE) return;
    int sub = threadIdx.x & 31;
    int is64 = *flag;
    int row = load_idx(ei, e, is64);
    int col = load_idx(ei, (long long)EE + e, is64);
    float nrm = dinv[row] * wt[e] * dinv[col];
    const float* xr = xw + (long long)row * 96;
    float* ar = agg + (long long)col * 96;
    atomicAdd(ar + sub,      nrm * xr[sub]);
    atomicAdd(ar + sub + 32, nrm * xr[sub + 32]);
    atomicAdd(ar + sub + 64, nrm * xr[sub + 64]);
}

// ---------------- gates + head: per node, 32 lanes ----------------
__global__ __launch_bounds__(256) void gate_kernel(
        const float* __restrict__ agg, const float* __restrict__ xw,
        const float* __restrict__ dinv, const float* __restrict__ hprev,
        const float* __restrict__ bcz, const float* __restrict__ bcr, const float* __restrict__ bch,
        const float* __restrict__ Wlz, const float* __restrict__ blz,
        const float* __restrict__ Wlr, const float* __restrict__ blr,
        const float* __restrict__ Wlh, const float* __restrict__ blh,
        const float* __restrict__ Whead, const float* __restrict__ bhead,
        float* __restrict__ y, float* __restrict__ hnew) {
    // Wl* are [32][64] row-major; store transposed: WT[k*32 + j] = Wl[j*64 + k]
    __shared__ float WzT[64 * 32], WrT[64 * 32], WhT[64 * 32];
    __shared__ float czs[8][32], crs[8][32], chs[8][32], hps[8][32], rhs[8][32];
    int tid = threadIdx.x;
    for (int e = tid; e < 2048; e += 256) {
        int j = e >> 6, k = e & 63;
        WzT[k * 32 + j] = Wlz[e];
        WrT[k * 32 + j] = Wlr[e];
        WhT[k * 32 + j] = Wlh[e];
    }
    int s = tid >> 5, j = tid & 31;
    int i = blockIdx.x * 8 + s;
    float hp = 0.f;
    if (i < NN) {
        float di = dinv[i];
        float sl = di * di;  // self-loop norm
        const float* ar = agg + (long long)i * 96;
        const float* xr = xw + (long long)i * 96;
        czs[s][j] = ar[j]      + sl * xr[j]      + bcz[j];
        crs[s][j] = ar[j + 32] + sl * xr[j + 32] + bcr[j];
        chs[s][j] = ar[j + 64] + sl * xr[j + 64] + bch[j];
        hp = hprev[(long long)i * HD + j];
        hps[s][j] = hp;
    }
    __syncthreads();
    float az = blz[j], arv = blr[j];
#pragma unroll
    for (int k = 0; k < 32; k++) {
        az  = fmaf(WzT[k * 32 + j], czs[s][k], az);
        arv = fmaf(WrT[k * 32 + j], crs[s][k], arv);
    }
#pragma unroll
    for (int k = 0; k < 32; k++) {
        float v = hps[s][k];
        az  = fmaf(WzT[(k + 32) * 32 + j], v, az);
        arv = fmaf(WrT[(k + 32) * 32 + j], v, arv);
    }
    float Z = 1.f / (1.f + __expf(-az));
    float R = 1.f / (1.f + __expf(-arv));
    rhs[s][j] = hp * R;
    __syncthreads();
    float ah = blh[j];
#pragma unroll
    for (int k = 0; k < 32; k++) ah = fmaf(WhT[k * 32 + j], chs[s][k], ah);
#pragma unroll
    for (int k = 0; k < 32; k++) ah = fmaf(WhT[(k + 32) * 32 + j], rhs[s][k], ah);
    float Ht = tanhf(ah);
    float hn = Z * hp + (1.f - Z) * Ht;
    float yv = fmaxf(hn, 0.f) * Whead[j];
#pragma unroll
    for (int m = 16; m; m >>= 1) yv += __shfl_xor(yv, m, 32);
    if (i < NN) {
        hnew[(long long)i * HD + j] = hn;
        if (j == 0) y[i] = yv + bhead[0];
    }
}

extern "C" void kernel_launch(void* const* d_in, const int* in_sizes, int n_in,
                              void* d_out, int out_size, void* d_ws, size_t ws_size,
                              hipStream_t stream) {
    const float* x     = (const float*)d_in[0];
    const int*   ei    = (const int*)d_in[1];
    const float* wt    = (const float*)d_in[2];
    const float* hprev = (const float*)d_in[3];
    const float* Wcz = (const float*)d_in[4],  *bcz = (const float*)d_in[5];
    const float* Wlz = (const float*)d_in[6],  *blz = (const float*)d_in[7];
    const float* Wcr = (const float*)d_in[8],  *bcr = (const float*)d_in[9];
    const float* Wlr = (const float*)d_in[10], *blr = (const float*)d_in[11];
    const float* Wch = (const float*)d_in[12], *bch = (const float*)d_in[13];
    const float* Wlh = (const float*)d_in[14], *blh = (const float*)d_in[15];
    const float* Whead = (const float*)d_in[16], *bhead = (const float*)d_in[17];

    float* out_y = (float*)d_out;            // [N]
    float* out_h = (float*)d_out + NN;       // [N,32]

    float* ws = (float*)d_ws;
    float* deg  = ws;                         // N
    float* dinv = ws + NN;                    // N
    float* xw   = ws + 2LL * NN;              // N*96
    float* agg  = ws + 98LL * NN;             // N*96
    int*   flag = (int*)(ws + 194LL * NN);    // 1

    detect_kernel<<<1, 64, 0, stream>>>((const unsigned int*)ei, flag);
    deg_init_kernel<<<(NN + 255) / 256, 256, 0, stream>>>(deg);
    hipMemsetAsync(agg, 0, (size_t)NN * 96 * sizeof(float), stream);
    deg_accum_kernel<<<(EE + 255) / 256, 256, 0, stream>>>(ei, wt, deg, flag);
    dinv_kernel<<<(NN + 255) / 256, 256, 0, stream>>>(deg, dinv);
    gemm_xw_kernel<<<(NN + 127) / 128, 256, 0, stream>>>(x, Wcz, Wcr, Wch, xw);
    scatter_kernel<<<(int)(((long long)EE * 32 + 255) / 256), 256, 0, stream>>>(
        ei, wt, dinv, xw, agg, flag);
    gate_kernel<<<(NN + 7) / 8, 256, 0, stream>>>(
        agg, xw, dinv, hprev, bcz, bcr, bch,
        Wlz, blz, Wlr, blr, Wlh, blh, Whead, bhead, out_y, out_h);
}

// Round 3
// 987.182 us; speedup vs baseline: 1.5261x; 1.5261x over previous
//
#include <hip/hip_runtime.h>

#define NN 100000
#define FIN 128
#define HD 32
#define EE 3200000
#define NB ((NN + 255) / 256)   // 391 blocks for node-sized arrays

// ---------------- dtype detect: edge_index int32 vs int64 ----------------
__global__ void detect_kernel(const unsigned int* __restrict__ ei32, int* __restrict__ flag) {
    int t = threadIdx.x;  // 0..63, single wave
    unsigned v = 0;
#pragma unroll
    for (int r = 0; r < 4; r++) v |= ei32[2 * (t + 64 * r) + 1];
    unsigned long long nz = __ballot(v != 0u);
    if (t == 0) *flag = (nz == 0ULL) ? 1 : 0;  // 1 => int64
}

__device__ __forceinline__ int load_idx(const int* ei, long long pos, int is64) {
    if (is64) return (int)((const long long*)ei)[pos];
    return ei[pos];
}

// ---------------- init: deg=1 (self-loop), cnt=0, cursor=0 ----------------
__global__ void init_kernel(float* __restrict__ deg, int* __restrict__ cnt, int* __restrict__ cursor) {
    int i = blockIdx.x * blockDim.x + threadIdx.x;
    if (i < NN) { deg[i] = 1.0f; cnt[i] = 0; cursor[i] = 0; }
}

// ---------------- edge pass 1: degree + destination histogram ----------------
__global__ void edge_pass1_kernel(const int* __restrict__ ei, const float* __restrict__ wt,
                                  float* __restrict__ deg, int* __restrict__ cnt,
                                  const int* __restrict__ flag) {
    int e = blockIdx.x * blockDim.x + threadIdx.x;
    if (e >= EE) return;
    int is64 = *flag;
    int col = load_idx(ei, (long long)EE + e, is64);
    atomicAdd(deg + col, wt[e]);
    atomicAdd(cnt + col, 1);
}

__global__ void dinv_kernel(const float* __restrict__ deg, float* __restrict__ dinv) {
    int i = blockIdx.x * blockDim.x + threadIdx.x;
    if (i < NN) {
        float d = deg[i];
        dinv[i] = d > 0.f ? rsqrtf(d) : 0.f;
    }
}

// ---------------- block-scan of cnt -> escan (inclusive within block) ----------------
__global__ void scan1_kernel(const int* __restrict__ cnt, int* __restrict__ escan,
                             int* __restrict__ bsum) {
    __shared__ int sd[256];
    int t = threadIdx.x, b = blockIdx.x;
    int i = b * 256 + t;
    int v = (i < NN) ? cnt[i] : 0;
    sd[t] = v;
    __syncthreads();
    for (int off = 1; off < 256; off <<= 1) {
        int x = (t >= off) ? sd[t - off] : 0;
        __syncthreads();
        sd[t] += x;
        __syncthreads();
    }
    if (i < NN) escan[i] = sd[t];
    if (t == 255) bsum[b] = sd[t];
}

__global__ void scan2_kernel(const int* __restrict__ bsum, int* __restrict__ boff) {
    __shared__ int sd[512];
    int t = threadIdx.x;
    int v = (t < NB) ? bsum[t] : 0;
    sd[t] = v;
    __syncthreads();
    for (int off = 1; off < 512; off <<= 1) {
        int x = (t >= off) ? sd[t - off] : 0;
        __syncthreads();
        sd[t] += x;
        __syncthreads();
    }
    if (t < NB) boff[t] = sd[t] - v;  // exclusive block offset
}

// escan[i] := exclusive global start = incl_in_block - cnt + block_offset
__global__ void scan3_kernel(int* __restrict__ escan, const int* __restrict__ cnt,
                             const int* __restrict__ boff) {
    int i = blockIdx.x * blockDim.x + threadIdx.x;
    if (i < NN) escan[i] = escan[i] - cnt[i] + boff[blockIdx.x];
}

// ---------------- reorder edges into destination buckets ----------------
__global__ void reorder_kernel(const int* __restrict__ ei, const float* __restrict__ wt,
                               const float* __restrict__ dinv, const int* __restrict__ estart,
                               int* __restrict__ cursor, float2* __restrict__ erec,
                               const int* __restrict__ flag) {
    int e = blockIdx.x * blockDim.x + threadIdx.x;
    if (e >= EE) return;
    int is64 = *flag;
    int row = load_idx(ei, e, is64);
    int col = load_idx(ei, (long long)EE + e, is64);
    float nrm = dinv[row] * wt[e] * dinv[col];
    int pos = estart[col] + atomicAdd(cursor + col, 1);
    float2 rec;
    rec.x = __int_as_float(row);
    rec.y = nrm;
    erec[pos] = rec;
}

// ---------------- xw = x @ [Wc_z | Wc_r | Wc_h]  (f32, LDS-tiled) ----------------
__global__ __launch_bounds__(256) void gemm_xw_kernel(
        const float* __restrict__ x,
        const float* __restrict__ Wz, const float* __restrict__ Wr, const float* __restrict__ Wh,
        float* __restrict__ xw) {
    __shared__ float Bs[128 * 96];   // Bs[k*96 + c], k is GLOBAL k (0..127)
    __shared__ float AsT[8 * 128];   // AsT[kk*128 + row], kk local (0..7)
    int tid = threadIdx.x;
    int tx = tid & 31, ty = tid >> 5;
    int rowBase = blockIdx.x * 128;

    for (int e = tid; e < 4096; e += 256) { int k = e >> 5, c = e & 31; Bs[k * 96 + c]      = Wz[e]; }
    for (int e = tid; e < 4096; e += 256) { int k = e >> 5, c = e & 31; Bs[k * 96 + 32 + c] = Wr[e]; }
    for (int e = tid; e < 4096; e += 256) { int k = e >> 5, c = e & 31; Bs[k * 96 + 64 + c] = Wh[e]; }

    float acc0[16], acc1[16], acc2[16];
#pragma unroll
    for (int r = 0; r < 16; r++) { acc0[r] = 0.f; acc1[r] = 0.f; acc2[r] = 0.f; }

    int lr = tid >> 1;
    int lc = (tid & 1) * 4;
    for (int k0 = 0; k0 < 128; k0 += 8) {
        __syncthreads();
        int gr = rowBase + lr;
        float4 a4 = make_float4(0.f, 0.f, 0.f, 0.f);
        if (gr < NN) a4 = *(const float4*)(x + (long long)gr * FIN + k0 + lc);
        AsT[(lc + 0) * 128 + lr] = a4.x;
        AsT[(lc + 1) * 128 + lr] = a4.y;
        AsT[(lc + 2) * 128 + lr] = a4.z;
        AsT[(lc + 3) * 128 + lr] = a4.w;
        __syncthreads();
#pragma unroll
        for (int kk = 0; kk < 8; kk++) {
            float b0 = Bs[(k0 + kk) * 96 + tx];
            float b1 = Bs[(k0 + kk) * 96 + 32 + tx];
            float b2 = Bs[(k0 + kk) * 96 + 64 + tx];
            const float4* ap = (const float4*)(AsT + kk * 128 + ty * 16);
            float4 a0 = ap[0], a1 = ap[1], a2 = ap[2], a3 = ap[3];
            float av[16] = {a0.x,a0.y,a0.z,a0.w, a1.x,a1.y,a1.z,a1.w,
                            a2.x,a2.y,a2.z,a2.w, a3.x,a3.y,a3.z,a3.w};
#pragma unroll
            for (int r = 0; r < 16; r++) {
                acc0[r] = fmaf(av[r], b0, acc0[r]);
                acc1[r] = fmaf(av[r], b1, acc1[r]);
                acc2[r] = fmaf(av[r], b2, acc2[r]);
            }
        }
    }
#pragma unroll
    for (int r = 0; r < 16; r++) {
        int gr = rowBase + ty * 16 + r;
        if (gr < NN) {
            float* o = xw + (long long)gr * 96;
            o[tx] = acc0[r]; o[tx + 32] = acc1[r]; o[tx + 64] = acc2[r];
        }
    }
}

// ---------------- fused gather-aggregate + GRU gates + head ----------------
// 32-lane group per node; 8 nodes/block; NN = 12500*8 exactly.
__global__ __launch_bounds__(256) void agg_gate_kernel(
        const float2* __restrict__ erec, const int* __restrict__ estart, const int* __restrict__ cnt,
        const float* __restrict__ xw, const float* __restrict__ dinv,
        const float* __restrict__ hprev,
        const float* __restrict__ bcz, const float* __restrict__ bcr, const float* __restrict__ bch,
        const float* __restrict__ Wlz, const float* __restrict__ blz,
        const float* __restrict__ Wlr, const float* __restrict__ blr,
        const float* __restrict__ Wlh, const float* __restrict__ blh,
        const float* __restrict__ Whead, const float* __restrict__ bhead,
        float* __restrict__ y, float* __restrict__ hnew) {
    __shared__ float WzT[64 * 32], WrT[64 * 32], WhT[64 * 32];  // WT[k*32+j] = Wl[j*64+k]
    __shared__ float czs[8][32], crs[8][32], chs[8][32], hps[8][32], rhs[8][32];
    int tid = threadIdx.x;
    for (int e2 = tid; e2 < 2048; e2 += 256) {
        int jj = e2 >> 6, k = e2 & 63;
        WzT[k * 32 + jj] = Wlz[e2];
        WrT[k * 32 + jj] = Wlr[e2];
        WhT[k * 32 + jj] = Wlh[e2];
    }
    int s = tid >> 5, j = tid & 31;
    int i = blockIdx.x * 8 + s;
    int beg = estart[i], c = cnt[i], end = beg + c;

    float cz = 0.f, cr = 0.f, ch = 0.f;
    for (int base = beg; base < end; base += 32) {
        int e = base + j;
        int r = 0; float nm = 0.f;
        if (e < end) { float2 rec = erec[e]; r = __float_as_int(rec.x); nm = rec.y; }
        int m = end - base; if (m > 32) m = 32;
        for (int t = 0; t < m; t++) {
            int row = __shfl(r, t, 32);
            float w  = __shfl(nm, t, 32);
            const float* xr = xw + (long long)row * 96;
            cz = fmaf(w, xr[j], cz);
            cr = fmaf(w, xr[j + 32], cr);
            ch = fmaf(w, xr[j + 64], ch);
        }
    }
    // self-loop (norm = dinv[i]^2 * 1) + bias
    float di = dinv[i], sl = di * di;
    const float* xi = xw + (long long)i * 96;
    czs[s][j] = fmaf(sl, xi[j],      cz) + bcz[j];
    crs[s][j] = fmaf(sl, xi[j + 32], cr) + bcr[j];
    chs[s][j] = fmaf(sl, xi[j + 64], ch) + bch[j];
    float hp = hprev[(long long)i * HD + j];
    hps[s][j] = hp;
    __syncthreads();

    float az = blz[j], arv = blr[j];
#pragma unroll
    for (int k = 0; k < 32; k++) {
        az  = fmaf(WzT[k * 32 + j], czs[s][k], az);
        arv = fmaf(WrT[k * 32 + j], crs[s][k], arv);
    }
#pragma unroll
    for (int k = 0; k < 32; k++) {
        float v = hps[s][k];
        az  = fmaf(WzT[(k + 32) * 32 + j], v, az);
        arv = fmaf(WrT[(k + 32) * 32 + j], v, arv);
    }
    float Z = 1.f / (1.f + __expf(-az));
    float R = 1.f / (1.f + __expf(-arv));
    rhs[s][j] = hp * R;
    __syncthreads();

    float ah = blh[j];
#pragma unroll
    for (int k = 0; k < 32; k++) ah = fmaf(WhT[k * 32 + j], chs[s][k], ah);
#pragma unroll
    for (int k = 0; k < 32; k++) ah = fmaf(WhT[(k + 32) * 32 + j], rhs[s][k], ah);
    float Ht = tanhf(ah);
    float hn = Z * hp + (1.f - Z) * Ht;
    float yv = fmaxf(hn, 0.f) * Whead[j];
#pragma unroll
    for (int m = 16; m; m >>= 1) yv += __shfl_xor(yv, m, 32);
    hnew[(long long)i * HD + j] = hn;
    if (j == 0) y[i] = yv + bhead[0];
}

extern "C" void kernel_launch(void* const* d_in, const int* in_sizes, int n_in,
                              void* d_out, int out_size, void* d_ws, size_t ws_size,
                              hipStream_t stream) {
    const float* x     = (const float*)d_in[0];
    const int*   ei    = (const int*)d_in[1];
    const float* wt    = (const float*)d_in[2];
    const float* hprev = (const float*)d_in[3];
    const float* Wcz = (const float*)d_in[4],  *bcz = (const float*)d_in[5];
    const float* Wlz = (const float*)d_in[6],  *blz = (const float*)d_in[7];
    const float* Wcr = (const float*)d_in[8],  *bcr = (const float*)d_in[9];
    const float* Wlr = (const float*)d_in[10], *blr = (const float*)d_in[11];
    const float* Wch = (const float*)d_in[12], *bch = (const float*)d_in[13];
    const float* Wlh = (const float*)d_in[14], *blh = (const float*)d_in[15];
    const float* Whead = (const float*)d_in[16], *bhead = (const float*)d_in[17];

    float* out_y = (float*)d_out;            // [N]
    float* out_h = (float*)d_out + NN;       // [N,32]

    float* ws = (float*)d_ws;
    float* deg    = ws;                        // NN f32
    float* dinv   = ws + NN;                   // NN f32
    float* xw     = ws + 2LL * NN;             // 96*NN f32
    int*   escan  = (int*)(ws + 98LL * NN);    // NN int (scan -> estart)
    int*   cnt    = (int*)(ws + 99LL * NN);    // NN int
    int*   cursor = (int*)(ws + 100LL * NN);   // NN int
    int*   bsum   = (int*)(ws + 101LL * NN);   // 512 int
    int*   boff   = bsum + 512;                // 512 int
    int*   flag   = boff + 512;                // 1 int
    float2* erec  = (float2*)(ws + 102LL * NN);// EE float2 (offset 40.8MB, 8B-aligned)

    detect_kernel<<<1, 64, 0, stream>>>((const unsigned int*)ei, flag);
    init_kernel<<<NB, 256, 0, stream>>>(deg, cnt, cursor);
    edge_pass1_kernel<<<(EE + 255) / 256, 256, 0, stream>>>(ei, wt, deg, cnt, flag);
    dinv_kernel<<<NB, 256, 0, stream>>>(deg, dinv);
    scan1_kernel<<<NB, 256, 0, stream>>>(cnt, escan, bsum);
    scan2_kernel<<<1, 512, 0, stream>>>(bsum, boff);
    scan3_kernel<<<NB, 256, 0, stream>>>(escan, cnt, boff);
    gemm_xw_kernel<<<(NN + 127) / 128, 256, 0, stream>>>(x, Wcz, Wcr, Wch, xw);
    reorder_kernel<<<(EE + 255) / 256, 256, 0, stream>>>(ei, wt, dinv, escan, cursor, erec, flag);
    agg_gate_kernel<<<NN / 8, 256, 0, stream>>>(
        erec, escan, cnt, xw, dinv, hprev, bcz, bcr, bch,
        Wlz, blz, Wlr, blr, Wlh, blh, Whead, bhead, out_y, out_h);
}

// Round 4
// 799.467 us; speedup vs baseline: 1.8844x; 1.2348x over previous
//
#include <hip/hip_runtime.h>

#define NN 100000
#define FIN 128
#define HD 32
#define EE 3200000
#define NB ((NN + 255) / 256)   // 391 blocks for node-sized arrays

typedef unsigned int uint;
typedef unsigned short ushort;

__device__ __forceinline__ ushort f2bf(float f) {
    uint b = __float_as_uint(f);
    return (ushort)((b + 0x7FFFu + ((b >> 16) & 1u)) >> 16);
}
__device__ __forceinline__ float bf2f(ushort u) {
    return __uint_as_float(((uint)u) << 16);
}

// ---------------- dtype detect: edge_index int32 vs int64 ----------------
__global__ void detect_kernel(const uint* __restrict__ ei32, int* __restrict__ flag) {
    int t = threadIdx.x;  // 0..63, single wave
    uint v = 0;
#pragma unroll
    for (int r = 0; r < 4; r++) v |= ei32[2 * (t + 64 * r) + 1];
    unsigned long long nz = __ballot(v != 0u);
    if (t == 0) *flag = (nz == 0ULL) ? 1 : 0;  // 1 => int64
}

__device__ __forceinline__ int load_idx(const int* ei, long long pos, int is64) {
    if (is64) return (int)((const long long*)ei)[pos];
    return ei[pos];
}

// ---------------- init: deg=1 (self-loop), cnt=0, cursor=0 ----------------
__global__ void init_kernel(float* __restrict__ deg, int* __restrict__ cnt, int* __restrict__ cursor) {
    int i = blockIdx.x * blockDim.x + threadIdx.x;
    if (i < NN) { deg[i] = 1.0f; cnt[i] = 0; cursor[i] = 0; }
}

// ---------------- edge pass 1: degree + destination histogram ----------------
__global__ void edge_pass1_kernel(const int* __restrict__ ei, const float* __restrict__ wt,
                                  float* __restrict__ deg, int* __restrict__ cnt,
                                  const int* __restrict__ flag) {
    int e = blockIdx.x * blockDim.x + threadIdx.x;
    if (e >= EE) return;
    int is64 = *flag;
    int col = load_idx(ei, (long long)EE + e, is64);
    atomicAdd(deg + col, wt[e]);
    atomicAdd(cnt + col, 1);
}

__global__ void dinv_kernel(const float* __restrict__ deg, float* __restrict__ dinv) {
    int i = blockIdx.x * blockDim.x + threadIdx.x;
    if (i < NN) {
        float d = deg[i];
        dinv[i] = d > 0.f ? rsqrtf(d) : 0.f;
    }
}

// ---------------- block-scan of cnt -> escan ----------------
__global__ void scan1_kernel(const int* __restrict__ cnt, int* __restrict__ escan,
                             int* __restrict__ bsum) {
    __shared__ int sd[256];
    int t = threadIdx.x, b = blockIdx.x;
    int i = b * 256 + t;
    int v = (i < NN) ? cnt[i] : 0;
    sd[t] = v;
    __syncthreads();
    for (int off = 1; off < 256; off <<= 1) {
        int x = (t >= off) ? sd[t - off] : 0;
        __syncthreads();
        sd[t] += x;
        __syncthreads();
    }
    if (i < NN) escan[i] = sd[t];
    if (t == 255) bsum[b] = sd[t];
}

__global__ void scan2_kernel(const int* __restrict__ bsum, int* __restrict__ boff) {
    __shared__ int sd[512];
    int t = threadIdx.x;
    int v = (t < NB) ? bsum[t] : 0;
    sd[t] = v;
    __syncthreads();
    for (int off = 1; off < 512; off <<= 1) {
        int x = (t >= off) ? sd[t - off] : 0;
        __syncthreads();
        sd[t] += x;
        __syncthreads();
    }
    if (t < NB) boff[t] = sd[t] - v;  // exclusive block offset
}

__global__ void scan3_kernel(int* __restrict__ escan, const int* __restrict__ cnt,
                             const int* __restrict__ boff) {
    int i = blockIdx.x * blockDim.x + threadIdx.x;
    if (i < NN) escan[i] = escan[i] - cnt[i] + boff[blockIdx.x];
}

// ---------------- reorder edges into destination buckets (packed 4B records) ----
// rec = row (17 bits) | bf16(norm) sans sign (15 bits) << 17
__global__ void reorder_kernel(const int* __restrict__ ei, const float* __restrict__ wt,
                               const float* __restrict__ dinv, const int* __restrict__ estart,
                               int* __restrict__ cursor, uint* __restrict__ erecp,
                               const int* __restrict__ flag) {
    int e = blockIdx.x * blockDim.x + threadIdx.x;
    if (e >= EE) return;
    int is64 = *flag;
    int row = load_idx(ei, e, is64);
    int col = load_idx(ei, (long long)EE + e, is64);
    float nrm = dinv[row] * wt[e] * dinv[col];
    uint nb = __float_as_uint(nrm);
    uint enc = ((nb + 0x8000u) >> 16) & 0x7FFFu;   // round-to-nearest bf16, drop sign(=0)
    int pos = estart[col] + atomicAdd(cursor + col, 1);
    erecp[pos] = (uint)row | (enc << 17);
}

// ---------------- xw = x @ [Wc_z | Wc_r | Wc_h]  (f32 VALU, bf16 output) -------
// Output layout per node (96 ushort): [z0,r0, z1,r1, ..., z31,r31, h0..h31]
__global__ __launch_bounds__(256) void gemm_xw_kernel(
        const float* __restrict__ x,
        const float* __restrict__ Wz, const float* __restrict__ Wr, const float* __restrict__ Wh,
        ushort* __restrict__ xw16) {
    __shared__ float Bs[128 * 96];   // Bs[k*96 + c], k GLOBAL (0..127)
    __shared__ float AsT[8 * 128];   // AsT[kk*128 + row], kk local (0..7)
    int tid = threadIdx.x;
    int tx = tid & 31, ty = tid >> 5;
    int rowBase = blockIdx.x * 128;

    for (int e = tid; e < 4096; e += 256) { int k = e >> 5, c = e & 31; Bs[k * 96 + c]      = Wz[e]; }
    for (int e = tid; e < 4096; e += 256) { int k = e >> 5, c = e & 31; Bs[k * 96 + 32 + c] = Wr[e]; }
    for (int e = tid; e < 4096; e += 256) { int k = e >> 5, c = e & 31; Bs[k * 96 + 64 + c] = Wh[e]; }

    float acc0[16], acc1[16], acc2[16];
#pragma unroll
    for (int r = 0; r < 16; r++) { acc0[r] = 0.f; acc1[r] = 0.f; acc2[r] = 0.f; }

    int lr = tid >> 1;
    int lc = (tid & 1) * 4;
    for (int k0 = 0; k0 < 128; k0 += 8) {
        __syncthreads();
        int gr = rowBase + lr;
        float4 a4 = make_float4(0.f, 0.f, 0.f, 0.f);
        if (gr < NN) a4 = *(const float4*)(x + (long long)gr * FIN + k0 + lc);
        AsT[(lc + 0) * 128 + lr] = a4.x;
        AsT[(lc + 1) * 128 + lr] = a4.y;
        AsT[(lc + 2) * 128 + lr] = a4.z;
        AsT[(lc + 3) * 128 + lr] = a4.w;
        __syncthreads();
#pragma unroll
        for (int kk = 0; kk < 8; kk++) {
            float b0 = Bs[(k0 + kk) * 96 + tx];
            float b1 = Bs[(k0 + kk) * 96 + 32 + tx];
            float b2 = Bs[(k0 + kk) * 96 + 64 + tx];
            const float4* ap = (const float4*)(AsT + kk * 128 + ty * 16);
            float4 a0 = ap[0], a1 = ap[1], a2 = ap[2], a3 = ap[3];
            float av[16] = {a0.x,a0.y,a0.z,a0.w, a1.x,a1.y,a1.z,a1.w,
                            a2.x,a2.y,a2.z,a2.w, a3.x,a3.y,a3.z,a3.w};
#pragma unroll
            for (int r = 0; r < 16; r++) {
                acc0[r] = fmaf(av[r], b0, acc0[r]);
                acc1[r] = fmaf(av[r], b1, acc1[r]);
                acc2[r] = fmaf(av[r], b2, acc2[r]);
            }
        }
    }
#pragma unroll
    for (int r = 0; r < 16; r++) {
        int gr = rowBase + ty * 16 + r;
        if (gr < NN) {
            ushort* o = xw16 + (long long)gr * 96;
            uint zr = (uint)f2bf(acc0[r]) | ((uint)f2bf(acc1[r]) << 16);
            *(uint*)(o + 2 * tx) = zr;      // 4B coalesced
            o[64 + tx] = f2bf(acc2[r]);     // 2B
        }
    }
}

// ---------------- fused gather-aggregate + GRU gates + head ----------------
// 32-lane group per node; 16 nodes / 512-thread block; NN = 6250*16 exactly.
// LDS 36.9KB -> 4 blocks/CU x 8 waves = 32 waves (100% cap).
__global__ __launch_bounds__(512) void agg_gate_kernel(
        const uint* __restrict__ erecp, const int* __restrict__ estart, const int* __restrict__ cnt,
        const ushort* __restrict__ xw16, const float* __restrict__ dinv,
        const float* __restrict__ hprev,
        const float* __restrict__ bcz, const float* __restrict__ bcr, const float* __restrict__ bch,
        const float* __restrict__ Wlz, const float* __restrict__ blz,
        const float* __restrict__ Wlr, const float* __restrict__ blr,
        const float* __restrict__ Wlh, const float* __restrict__ blh,
        const float* __restrict__ Whead, const float* __restrict__ bhead,
        float* __restrict__ y, float* __restrict__ hnew) {
    __shared__ float WzT[64 * 32], WrT[64 * 32], WhT[64 * 32];  // WT[k*32+j] = Wl[j*64+k]
    __shared__ float czs[16][32], crs[16][32], chs[16][32], hps[16][32], rhs[16][32];
    __shared__ uint recs[16][32];   // per-node-group record staging (uniform-read broadcast)
    int tid = threadIdx.x;
    for (int e2 = tid; e2 < 2048; e2 += 512) {
        int jj = e2 >> 6, k = e2 & 63;
        WzT[k * 32 + jj] = Wlz[e2];
        WrT[k * 32 + jj] = Wlr[e2];
        WhT[k * 32 + jj] = Wlh[e2];
    }
    int s = tid >> 5, j = tid & 31;
    int i = blockIdx.x * 16 + s;
    int beg = estart[i], c = cnt[i], end = beg + c;

    float cz = 0.f, cr = 0.f, ch = 0.f;
    for (int base = beg; base < end; base += 32) {
        int e = base + j;
        if (e < end) recs[s][j] = erecp[e];   // coalesced 128B per group
        int mm = end - base; if (mm > 32) mm = 32;
        // Within-wave LDS RAW: DS ops from one wave complete in order; readers are
        // the same 32-lane group that wrote. Uniform-address reads -> broadcast,
        // no ds_bpermute one-bank pathology (R3: 7.4e7 conflict cycles).
        for (int t = 0; t < mm; t++) {
            uint v = recs[s][t];
            int row = (int)(v & 0x1FFFFu);
            float w = __uint_as_float((v >> 17) << 16);
            const ushort* xr = xw16 + (long long)row * 96;
            uint zr = *(const uint*)(xr + 2 * j);
            float fz = __uint_as_float(zr << 16);
            float fr = __uint_as_float(zr & 0xFFFF0000u);
            float fh = bf2f(xr[64 + j]);
            cz = fmaf(w, fz, cz);
            cr = fmaf(w, fr, cr);
            ch = fmaf(w, fh, ch);
        }
    }
    // self-loop (norm = dinv[i]^2) + bias
    float di = dinv[i], sl = di * di;
    const ushort* xi = xw16 + (long long)i * 96;
    uint zri = *(const uint*)(xi + 2 * j);
    czs[s][j] = fmaf(sl, __uint_as_float(zri << 16),        cz) + bcz[j];
    crs[s][j] = fmaf(sl, __uint_as_float(zri & 0xFFFF0000u), cr) + bcr[j];
    chs[s][j] = fmaf(sl, bf2f(xi[64 + j]),                   ch) + bch[j];
    float hp = hprev[(long long)i * HD + j];
    hps[s][j] = hp;
    __syncthreads();

    float az = blz[j], arv = blr[j];
#pragma unroll
    for (int k = 0; k < 32; k++) {
        az  = fmaf(WzT[k * 32 + j], czs[s][k], az);
        arv = fmaf(WrT[k * 32 + j], crs[s][k], arv);
    }
#pragma unroll
    for (int k = 0; k < 32; k++) {
        float v = hps[s][k];
        az  = fmaf(WzT[(k + 32) * 32 + j], v, az);
        arv = fmaf(WrT[(k + 32) * 32 + j], v, arv);
    }
    float Z = 1.f / (1.f + __expf(-az));
    float R = 1.f / (1.f + __expf(-arv));
    rhs[s][j] = hp * R;
    __syncthreads();

    float ah = blh[j];
#pragma unroll
    for (int k = 0; k < 32; k++) ah = fmaf(WhT[k * 32 + j], chs[s][k], ah);
#pragma unroll
    for (int k = 0; k < 32; k++) ah = fmaf(WhT[(k + 32) * 32 + j], rhs[s][k], ah);
    float Ht = tanhf(ah);
    float hn = Z * hp + (1.f - Z) * Ht;
    float yv = fmaxf(hn, 0.f) * Whead[j];
#pragma unroll
    for (int m = 16; m; m >>= 1) yv += __shfl_xor(yv, m, 32);
    hnew[(long long)i * HD + j] = hn;
    if (j == 0) y[i] = yv + bhead[0];
}

extern "C" void kernel_launch(void* const* d_in, const int* in_sizes, int n_in,
                              void* d_out, int out_size, void* d_ws, size_t ws_size,
                              hipStream_t stream) {
    const float* x     = (const float*)d_in[0];
    const int*   ei    = (const int*)d_in[1];
    const float* wt    = (const float*)d_in[2];
    const float* hprev = (const float*)d_in[3];
    const float* Wcz = (const float*)d_in[4],  *bcz = (const float*)d_in[5];
    const float* Wlz = (const float*)d_in[6],  *blz = (const float*)d_in[7];
    const float* Wcr = (const float*)d_in[8],  *bcr = (const float*)d_in[9];
    const float* Wlr = (const float*)d_in[10], *blr = (const float*)d_in[11];
    const float* Wch = (const float*)d_in[12], *bch = (const float*)d_in[13];
    const float* Wlh = (const float*)d_in[14], *blh = (const float*)d_in[15];
    const float* Whead = (const float*)d_in[16], *bhead = (const float*)d_in[17];

    float* out_y = (float*)d_out;            // [N]
    float* out_h = (float*)d_out + NN;       // [N,32]

    float* ws = (float*)d_ws;
    float*  deg    = ws;                           // NN f32
    float*  dinv   = ws + NN;                      // NN f32
    int*    escan  = (int*)(ws + 2LL * NN);        // NN int
    int*    cnt    = (int*)(ws + 3LL * NN);        // NN int
    int*    cursor = (int*)(ws + 4LL * NN);        // NN int
    int*    bsum   = (int*)(ws + 5LL * NN);        // 512 int
    int*    boff   = bsum + 512;                   // 512 int
    int*    flag   = boff + 512;                   // 1 int
    ushort* xw16   = (ushort*)(ws + 6LL * NN);     // 96*NN ushort (19.2MB)
    uint*   erecp  = (uint*)(ws + 54LL * NN);      // EE uint (12.8MB)

    detect_kernel<<<1, 64, 0, stream>>>((const uint*)ei, flag);
    init_kernel<<<NB, 256, 0, stream>>>(deg, cnt, cursor);
    edge_pass1_kernel<<<(EE + 255) / 256, 256, 0, stream>>>(ei, wt, deg, cnt, flag);
    dinv_kernel<<<NB, 256, 0, stream>>>(deg, dinv);
    scan1_kernel<<<NB, 256, 0, stream>>>(cnt, escan, bsum);
    scan2_kernel<<<1, 512, 0, stream>>>(bsum, boff);
    scan3_kernel<<<NB, 256, 0, stream>>>(escan, cnt, boff);
    gemm_xw_kernel<<<(NN + 127) / 128, 256, 0, stream>>>(x, Wcz, Wcr, Wch, xw16);
    reorder_kernel<<<(EE + 255) / 256, 256, 0, stream>>>(ei, wt, dinv, escan, cursor, erecp, flag);
    agg_gate_kernel<<<NN / 16, 512, 0, stream>>>(
        erecp, escan, cnt, xw16, dinv, hprev, bcz, bcr, bch,
        Wlz, blz, Wlr, blr, Wlh, blh, Whead, bhead, out_y, out_h);
}

// Round 5
// 593.204 us; speedup vs baseline: 2.5397x; 1.3477x over previous
//
#include <hip/hip_runtime.h>

#define NN 100000
#define FIN 128
#define HD 32
#define EE 3200000
#define NB ((NN + 255) / 256)   // 391 blocks for node-sized arrays

typedef unsigned int uint;
typedef unsigned short ushort;

__device__ __forceinline__ ushort f2bf(float f) {
    uint b = __float_as_uint(f);
    return (ushort)((b + 0x7FFFu + ((b >> 16) & 1u)) >> 16);
}
__device__ __forceinline__ float bf2f(ushort u) {
    return __uint_as_float(((uint)u) << 16);
}

// ---------------- dtype detect: edge_index int32 vs int64 ----------------
__global__ void detect_kernel(const uint* __restrict__ ei32, int* __restrict__ flag) {
    int t = threadIdx.x;  // 0..63, single wave
    uint v = 0;
#pragma unroll
    for (int r = 0; r < 4; r++) v |= ei32[2 * (t + 64 * r) + 1];
    unsigned long long nz = __ballot(v != 0u);
    if (t == 0) *flag = (nz == 0ULL) ? 1 : 0;  // 1 => int64
}

__device__ __forceinline__ int load_idx(const int* ei, long long pos, int is64) {
    if (is64) return (int)((const long long*)ei)[pos];
    return ei[pos];
}

__global__ void init_kernel(int* __restrict__ cnt) {
    int i = blockIdx.x * blockDim.x + threadIdx.x;
    if (i < NN) cnt[i] = 0;
}

// ---------------- edge pass 1: histogram; atomic return = within-bucket rank ----
__global__ void edge_pass1_kernel(const int* __restrict__ ei, int* __restrict__ cnt,
                                  ushort* __restrict__ rank, const int* __restrict__ flag) {
    int e = blockIdx.x * blockDim.x + threadIdx.x;
    if (e >= EE) return;
    int is64 = *flag;
    int col = load_idx(ei, (long long)EE + e, is64);
    int r = atomicAdd(cnt + col, 1);
    rank[e] = (ushort)r;   // max degree ~70 << 65536
}

// ---------------- block-scan of cnt -> escan ----------------
__global__ void scan1_kernel(const int* __restrict__ cnt, int* __restrict__ escan,
                             int* __restrict__ bsum) {
    __shared__ int sd[256];
    int t = threadIdx.x, b = blockIdx.x;
    int i = b * 256 + t;
    int v = (i < NN) ? cnt[i] : 0;
    sd[t] = v;
    __syncthreads();
    for (int off = 1; off < 256; off <<= 1) {
        int x = (t >= off) ? sd[t - off] : 0;
        __syncthreads();
        sd[t] += x;
        __syncthreads();
    }
    if (i < NN) escan[i] = sd[t];
    if (t == 255) bsum[b] = sd[t];
}

__global__ void scan2_kernel(const int* __restrict__ bsum, int* __restrict__ boff) {
    __shared__ int sd[512];
    int t = threadIdx.x;
    int v = (t < NB) ? bsum[t] : 0;
    sd[t] = v;
    __syncthreads();
    for (int off = 1; off < 512; off <<= 1) {
        int x = (t >= off) ? sd[t - off] : 0;
        __syncthreads();
        sd[t] += x;
        __syncthreads();
    }
    if (t < NB) boff[t] = sd[t] - v;  // exclusive block offset
}

__global__ void scan3_kernel(int* __restrict__ escan, const int* __restrict__ cnt,
                             const int* __restrict__ boff) {
    int i = blockIdx.x * blockDim.x + threadIdx.x;
    if (i < NN) escan[i] = escan[i] - cnt[i] + boff[blockIdx.x];
}

// ---------------- reorder edges into destination buckets (no atomics) ----------
// rec = row (17 bits) | bf16(wt) sans sign (15 bits) << 17
__global__ void reorder_kernel(const int* __restrict__ ei, const float* __restrict__ wt,
                               const int* __restrict__ estart, const ushort* __restrict__ rank,
                               uint* __restrict__ erecp, const int* __restrict__ flag) {
    int e = blockIdx.x * blockDim.x + threadIdx.x;
    if (e >= EE) return;
    int is64 = *flag;
    int row = load_idx(ei, e, is64);
    int col = load_idx(ei, (long long)EE + e, is64);
    uint nb = __float_as_uint(wt[e]);
    uint enc = ((nb + 0x8000u) >> 16) & 0x7FFFu;   // bf16 round, drop sign(=0); wt<1 so no carry into sign
    int pos = estart[col] + (int)rank[e];
    erecp[pos] = (uint)row | (enc << 17);
}

// ---------------- per-node degree from bucketed weights (no atomics) ----------
// deg = 1 (self-loop) + sum of bucket wts; dinv = rsqrt(deg); deg >= 1 always.
__global__ void degsum_kernel(const uint* __restrict__ erecp, const int* __restrict__ estart,
                              const int* __restrict__ cnt, float* __restrict__ dinv) {
    int s = threadIdx.x >> 5, j = threadIdx.x & 31;
    int i = blockIdx.x * 8 + s;                 // NN % 8 == 0
    int beg = estart[i], end = beg + cnt[i];
    float sum = 0.f;
    for (int e = beg + j; e < end; e += 32) {
        uint v = erecp[e];
        sum += __uint_as_float((v >> 17) << 16);
    }
#pragma unroll
    for (int m = 16; m; m >>= 1) sum += __shfl_xor(sum, m, 32);
    if (j == 0) dinv[i] = rsqrtf(1.0f + sum);
}

// ---------------- xw = x @ [Wc_z | Wc_r | Wc_h]  (f32 VALU, bf16 output) -------
// Output layout per node (96 ushort): [z0,r0, z1,r1, ..., z31,r31, h0..h31]
__global__ __launch_bounds__(256) void gemm_xw_kernel(
        const float* __restrict__ x,
        const float* __restrict__ Wz, const float* __restrict__ Wr, const float* __restrict__ Wh,
        ushort* __restrict__ xw16) {
    __shared__ float Bs[128 * 96];   // Bs[k*96 + c], k GLOBAL (0..127)
    __shared__ float AsT[8 * 128];   // AsT[kk*128 + row], kk local (0..7)
    int tid = threadIdx.x;
    int tx = tid & 31, ty = tid >> 5;
    int rowBase = blockIdx.x * 128;

    for (int e = tid; e < 4096; e += 256) { int k = e >> 5, c = e & 31; Bs[k * 96 + c]      = Wz[e]; }
    for (int e = tid; e < 4096; e += 256) { int k = e >> 5, c = e & 31; Bs[k * 96 + 32 + c] = Wr[e]; }
    for (int e = tid; e < 4096; e += 256) { int k = e >> 5, c = e & 31; Bs[k * 96 + 64 + c] = Wh[e]; }

    float acc0[16], acc1[16], acc2[16];
#pragma unroll
    for (int r = 0; r < 16; r++) { acc0[r] = 0.f; acc1[r] = 0.f; acc2[r] = 0.f; }

    int lr = tid >> 1;
    int lc = (tid & 1) * 4;
    for (int k0 = 0; k0 < 128; k0 += 8) {
        __syncthreads();
        int gr = rowBase + lr;
        float4 a4 = make_float4(0.f, 0.f, 0.f, 0.f);
        if (gr < NN) a4 = *(const float4*)(x + (long long)gr * FIN + k0 + lc);
        AsT[(lc + 0) * 128 + lr] = a4.x;
        AsT[(lc + 1) * 128 + lr] = a4.y;
        AsT[(lc + 2) * 128 + lr] = a4.z;
        AsT[(lc + 3) * 128 + lr] = a4.w;
        __syncthreads();
#pragma unroll
        for (int kk = 0; kk < 8; kk++) {
            float b0 = Bs[(k0 + kk) * 96 + tx];
            float b1 = Bs[(k0 + kk) * 96 + 32 + tx];
            float b2 = Bs[(k0 + kk) * 96 + 64 + tx];
            const float4* ap = (const float4*)(AsT + kk * 128 + ty * 16);
            float4 a0 = ap[0], a1 = ap[1], a2 = ap[2], a3 = ap[3];
            float av[16] = {a0.x,a0.y,a0.z,a0.w, a1.x,a1.y,a1.z,a1.w,
                            a2.x,a2.y,a2.z,a2.w, a3.x,a3.y,a3.z,a3.w};
#pragma unroll
            for (int r = 0; r < 16; r++) {
                acc0[r] = fmaf(av[r], b0, acc0[r]);
                acc1[r] = fmaf(av[r], b1, acc1[r]);
                acc2[r] = fmaf(av[r], b2, acc2[r]);
            }
        }
    }
#pragma unroll
    for (int r = 0; r < 16; r++) {
        int gr = rowBase + ty * 16 + r;
        if (gr < NN) {
            ushort* o = xw16 + (long long)gr * 96;
            uint zr = (uint)f2bf(acc0[r]) | ((uint)f2bf(acc1[r]) << 16);
            *(uint*)(o + 2 * tx) = zr;      // 4B coalesced
            o[64 + tx] = f2bf(acc2[r]);     // 2B
        }
    }
}

// ---------------- fused gather-aggregate + GRU gates + head ----------------
// 32-lane group per node; 16 nodes / 512-thread block; NN = 6250*16 exactly.
// norm = dinv[col] * (wt * dinv[row]); dinv[col] factored out of the sum.
__global__ __launch_bounds__(512) void agg_gate_kernel(
        const uint* __restrict__ erecp, const int* __restrict__ estart, const int* __restrict__ cnt,
        const ushort* __restrict__ xw16, const float* __restrict__ dinv,
        const float* __restrict__ hprev,
        const float* __restrict__ bcz, const float* __restrict__ bcr, const float* __restrict__ bch,
        const float* __restrict__ Wlz, const float* __restrict__ blz,
        const float* __restrict__ Wlr, const float* __restrict__ blr,
        const float* __restrict__ Wlh, const float* __restrict__ blh,
        const float* __restrict__ Whead, const float* __restrict__ bhead,
        float* __restrict__ y, float* __restrict__ hnew) {
    __shared__ float WzT[64 * 32], WrT[64 * 32], WhT[64 * 32];  // WT[k*32+j] = Wl[j*64+k]
    __shared__ float czs[16][32], crs[16][32], chs[16][32], hps[16][32], rhs[16][32];
    __shared__ uint  rows[16][32];   // staged row indices (uniform-read broadcast)
    __shared__ float wfs[16][32];    // staged wt*dinv[row]
    int tid = threadIdx.x;
    for (int e2 = tid; e2 < 2048; e2 += 512) {
        int jj = e2 >> 6, k = e2 & 63;
        WzT[k * 32 + jj] = Wlz[e2];
        WrT[k * 32 + jj] = Wlr[e2];
        WhT[k * 32 + jj] = Wlh[e2];
    }
    int s = tid >> 5, j = tid & 31;
    int i = blockIdx.x * 16 + s;
    int beg = estart[i], c = cnt[i], end = beg + c;

    float cz = 0.f, cr = 0.f, ch = 0.f;
    for (int base = beg; base < end; base += 32) {
        int e = base + j;
        if (e < end) {
            uint v = erecp[e];                    // coalesced 128B per group
            int row = (int)(v & 0x1FFFFu);
            float w = __uint_as_float((v >> 17) << 16);
            rows[s][j] = (uint)row;
            wfs[s][j] = w * dinv[row];            // L2-resident 400KB gather
        }
        int mm = end - base; if (mm > 32) mm = 32;
        // Same-group LDS RAW (in-order DS within a wave); uniform-address reads
        // broadcast conflict-free.
        for (int t = 0; t < mm; t++) {
            int row = (int)rows[s][t];
            float w = wfs[s][t];
            const ushort* xr = xw16 + (long long)row * 96;
            uint zr = *(const uint*)(xr + 2 * j);
            float fz = __uint_as_float(zr << 16);
            float fr = __uint_as_float(zr & 0xFFFF0000u);
            float fh = bf2f(xr[64 + j]);
            cz = fmaf(w, fz, cz);
            cr = fmaf(w, fr, cr);
            ch = fmaf(w, fh, ch);
        }
    }
    // apply dinv[col] factor; self-loop (norm = dinv^2) + bias
    float di = dinv[i], sl = di * di;
    const ushort* xi = xw16 + (long long)i * 96;
    uint zri = *(const uint*)(xi + 2 * j);
    czs[s][j] = fmaf(sl, __uint_as_float(zri << 16),         di * cz) + bcz[j];
    crs[s][j] = fmaf(sl, __uint_as_float(zri & 0xFFFF0000u), di * cr) + bcr[j];
    chs[s][j] = fmaf(sl, bf2f(xi[64 + j]),                   di * ch) + bch[j];
    float hp = hprev[(long long)i * HD + j];
    hps[s][j] = hp;
    __syncthreads();

    float az = blz[j], arv = blr[j];
#pragma unroll
    for (int k = 0; k < 32; k++) {
        az  = fmaf(WzT[k * 32 + j], czs[s][k], az);
        arv = fmaf(WrT[k * 32 + j], crs[s][k], arv);
    }
#pragma unroll
    for (int k = 0; k < 32; k++) {
        float v = hps[s][k];
        az  = fmaf(WzT[(k + 32) * 32 + j], v, az);
        arv = fmaf(WrT[(k + 32) * 32 + j], v, arv);
    }
    float Z = 1.f / (1.f + __expf(-az));
    float R = 1.f / (1.f + __expf(-arv));
    rhs[s][j] = hp * R;
    __syncthreads();

    float ah = blh[j];
#pragma unroll
    for (int k = 0; k < 32; k++) ah = fmaf(WhT[k * 32 + j], chs[s][k], ah);
#pragma unroll
    for (int k = 0; k < 32; k++) ah = fmaf(WhT[(k + 32) * 32 + j], rhs[s][k], ah);
    float Ht = tanhf(ah);
    float hn = Z * hp + (1.f - Z) * Ht;
    float yv = fmaxf(hn, 0.f) * Whead[j];
#pragma unroll
    for (int m = 16; m; m >>= 1) yv += __shfl_xor(yv, m, 32);
    hnew[(long long)i * HD + j] = hn;
    if (j == 0) y[i] = yv + bhead[0];
}

extern "C" void kernel_launch(void* const* d_in, const int* in_sizes, int n_in,
                              void* d_out, int out_size, void* d_ws, size_t ws_size,
                              hipStream_t stream) {
    const float* x     = (const float*)d_in[0];
    const int*   ei    = (const int*)d_in[1];
    const float* wt    = (const float*)d_in[2];
    const float* hprev = (const float*)d_in[3];
    const float* Wcz = (const float*)d_in[4],  *bcz = (const float*)d_in[5];
    const float* Wlz = (const float*)d_in[6],  *blz = (const float*)d_in[7];
    const float* Wcr = (const float*)d_in[8],  *bcr = (const float*)d_in[9];
    const float* Wlr = (const float*)d_in[10], *blr = (const float*)d_in[11];
    const float* Wch = (const float*)d_in[12], *bch = (const float*)d_in[13];
    const float* Wlh = (const float*)d_in[14], *blh = (const float*)d_in[15];
    const float* Whead = (const float*)d_in[16], *bhead = (const float*)d_in[17];

    float* out_y = (float*)d_out;            // [N]
    float* out_h = (float*)d_out + NN;       // [N,32]

    float* ws = (float*)d_ws;
    float*  dinv   = ws;                               // NN f32
    int*    escan  = (int*)(ws + NN);                  // NN int
    int*    cnt    = (int*)(ws + 2LL * NN);            // NN int
    int*    bsum   = (int*)(ws + 3LL * NN);            // 512 int
    int*    boff   = bsum + 512;                       // 512 int
    int*    flag   = boff + 512;                       // 1 int
    ushort* rank   = (ushort*)(ws + 4LL * NN);         // EE ushort (6.4MB)
    ushort* xw16   = (ushort*)(ws + 4LL * NN + EE / 2);// 96*NN ushort (19.2MB)
    uint*   erecp  = (uint*)(ws + 4LL * NN + EE / 2 + 48LL * NN);  // EE uint (12.8MB)

    detect_kernel<<<1, 64, 0, stream>>>((const uint*)ei, flag);
    init_kernel<<<NB, 256, 0, stream>>>(cnt);
    edge_pass1_kernel<<<(EE + 255) / 256, 256, 0, stream>>>(ei, cnt, rank, flag);
    scan1_kernel<<<NB, 256, 0, stream>>>(cnt, escan, bsum);
    scan2_kernel<<<1, 512, 0, stream>>>(bsum, boff);
    scan3_kernel<<<NB, 256, 0, stream>>>(escan, cnt, boff);
    gemm_xw_kernel<<<(NN + 127) / 128, 256, 0, stream>>>(x, Wcz, Wcr, Wch, xw16);
    reorder_kernel<<<(EE + 255) / 256, 256, 0, stream>>>(ei, wt, escan, rank, erecp, flag);
    degsum_kernel<<<NN / 8, 256, 0, stream>>>(erecp, escan, cnt, dinv);
    agg_gate_kernel<<<NN / 16, 512, 0, stream>>>(
        erecp, escan, cnt, xw16, dinv, hprev, bcz, bcr, bch,
        Wlz, blz, Wlr, blr, Wlh, blh, Whead, bhead, out_y, out_h);
}

// Round 6
// 555.855 us; speedup vs baseline: 2.7103x; 1.0672x over previous
//
#include <hip/hip_runtime.h>

#define NN 100000
#define FIN 128
#define HD 32
#define EE 3200000
#define CAP 80   // fixed bucket capacity; Poisson(32) P(deg>=80) ~ 1e-11/node
#define NB ((NN + 255) / 256)

typedef unsigned int uint;
typedef unsigned short ushort;

__device__ __forceinline__ ushort f2bf(float f) {
    uint b = __float_as_uint(f);
    return (ushort)((b + 0x7FFFu + ((b >> 16) & 1u)) >> 16);
}
__device__ __forceinline__ float bf2f(ushort u) {
    return __uint_as_float(((uint)u) << 16);
}

// ---------------- dtype detect: edge_index int32 vs int64 ----------------
__global__ void detect_kernel(const uint* __restrict__ ei32, int* __restrict__ flag) {
    int t = threadIdx.x;  // 0..63, single wave
    uint v = 0;
#pragma unroll
    for (int r = 0; r < 4; r++) v |= ei32[2 * (t + 64 * r) + 1];
    unsigned long long nz = __ballot(v != 0u);
    if (t == 0) *flag = (nz == 0ULL) ? 1 : 0;  // 1 => int64
}

__device__ __forceinline__ int load_idx(const int* ei, long long pos, int is64) {
    if (is64) return (int)((const long long*)ei)[pos];
    return ei[pos];
}

__global__ void init_kernel(int* __restrict__ cnt) {
    int i = blockIdx.x * blockDim.x + threadIdx.x;
    if (i < NN) cnt[i] = 0;
}

// ---------------- single edge pass: histogram atomic return = slot ----------
// rec = row (17 bits) | bf16(wt) sans sign (15 bits) << 17, placed directly at
// erecp[col*CAP + rank]. Eliminates the scan + reorder passes of R5.
__global__ void edge_bucket_kernel(const int* __restrict__ ei, const float* __restrict__ wt,
                                   int* __restrict__ cnt, uint* __restrict__ erecp,
                                   const int* __restrict__ flag) {
    int e = blockIdx.x * blockDim.x + threadIdx.x;
    if (e >= EE) return;
    int is64 = *flag;
    int row = load_idx(ei, e, is64);
    int col = load_idx(ei, (long long)EE + e, is64);
    uint nb = __float_as_uint(wt[e]);
    uint enc = ((nb + 0x8000u) >> 16) & 0x7FFFu;   // bf16 round, drop sign(=0)
    int r = atomicAdd(cnt + col, 1);               // within-bucket rank
    erecp[col * CAP + r] = (uint)row | (enc << 17);
}

// ---------------- per-node degree from bucketed weights (no atomics) ----------
__global__ void degsum_kernel(const uint* __restrict__ erecp, const int* __restrict__ cnt,
                              float* __restrict__ dinv) {
    int s = threadIdx.x >> 5, j = threadIdx.x & 31;
    int i = blockIdx.x * 8 + s;                 // NN % 8 == 0
    int beg = i * CAP, end = beg + cnt[i];
    float sum = 0.f;
    for (int e = beg + j; e < end; e += 32) {
        uint v = erecp[e];
        sum += __uint_as_float((v >> 17) << 16);
    }
#pragma unroll
    for (int m = 16; m; m >>= 1) sum += __shfl_xor(sum, m, 32);
    if (j == 0) dinv[i] = rsqrtf(1.0f + sum);   // 1 = self-loop weight
}

// ---------------- xw = x @ [Wc_z | Wc_r | Wc_h]  (f32 VALU, bf16 output) -------
// Output layout per node (96 ushort): [z0,r0, z1,r1, ..., z31,r31, h0..h31]
__global__ __launch_bounds__(256) void gemm_xw_kernel(
        const float* __restrict__ x,
        const float* __restrict__ Wz, const float* __restrict__ Wr, const float* __restrict__ Wh,
        ushort* __restrict__ xw16) {
    __shared__ float Bs[128 * 96];   // Bs[k*96 + c], k GLOBAL (0..127)
    __shared__ float AsT[8 * 128];   // AsT[kk*128 + row], kk local (0..7)
    int tid = threadIdx.x;
    int tx = tid & 31, ty = tid >> 5;
    int rowBase = blockIdx.x * 128;

    for (int e = tid; e < 4096; e += 256) { int k = e >> 5, c = e & 31; Bs[k * 96 + c]      = Wz[e]; }
    for (int e = tid; e < 4096; e += 256) { int k = e >> 5, c = e & 31; Bs[k * 96 + 32 + c] = Wr[e]; }
    for (int e = tid; e < 4096; e += 256) { int k = e >> 5, c = e & 31; Bs[k * 96 + 64 + c] = Wh[e]; }

    float acc0[16], acc1[16], acc2[16];
#pragma unroll
    for (int r = 0; r < 16; r++) { acc0[r] = 0.f; acc1[r] = 0.f; acc2[r] = 0.f; }

    int lr = tid >> 1;
    int lc = (tid & 1) * 4;
    for (int k0 = 0; k0 < 128; k0 += 8) {
        __syncthreads();
        int gr = rowBase + lr;
        float4 a4 = make_float4(0.f, 0.f, 0.f, 0.f);
        if (gr < NN) a4 = *(const float4*)(x + (long long)gr * FIN + k0 + lc);
        AsT[(lc + 0) * 128 + lr] = a4.x;
        AsT[(lc + 1) * 128 + lr] = a4.y;
        AsT[(lc + 2) * 128 + lr] = a4.z;
        AsT[(lc + 3) * 128 + lr] = a4.w;
        __syncthreads();
#pragma unroll
        for (int kk = 0; kk < 8; kk++) {
            float b0 = Bs[(k0 + kk) * 96 + tx];
            float b1 = Bs[(k0 + kk) * 96 + 32 + tx];
            float b2 = Bs[(k0 + kk) * 96 + 64 + tx];
            const float4* ap = (const float4*)(AsT + kk * 128 + ty * 16);
            float4 a0 = ap[0], a1 = ap[1], a2 = ap[2], a3 = ap[3];
            float av[16] = {a0.x,a0.y,a0.z,a0.w, a1.x,a1.y,a1.z,a1.w,
                            a2.x,a2.y,a2.z,a2.w, a3.x,a3.y,a3.z,a3.w};
#pragma unroll
            for (int r = 0; r < 16; r++) {
                acc0[r] = fmaf(av[r], b0, acc0[r]);
                acc1[r] = fmaf(av[r], b1, acc1[r]);
                acc2[r] = fmaf(av[r], b2, acc2[r]);
            }
        }
    }
#pragma unroll
    for (int r = 0; r < 16; r++) {
        int gr = rowBase + ty * 16 + r;
        if (gr < NN) {
            ushort* o = xw16 + (long long)gr * 96;
            uint zr = (uint)f2bf(acc0[r]) | ((uint)f2bf(acc1[r]) << 16);
            *(uint*)(o + 2 * tx) = zr;      // 4B coalesced
            o[64 + tx] = f2bf(acc2[r]);     // 2B
        }
    }
}

// ---------------- fused gather-aggregate + GRU gates + head ----------------
// 32-lane group per node; 16 nodes / 512-thread block; NN = 6250*16 exactly.
// norm = dinv[col] * (wt * dinv[row]); dinv[col] factored out of the sum.
// Gather loop 4x-unrolled: 12 independent global loads in flight per group
// (R5: VALUBusy 37% => latency-bound chain of 3 loads/edge).
__global__ __launch_bounds__(512) void agg_gate_kernel(
        const uint* __restrict__ erecp, const int* __restrict__ cnt,
        const ushort* __restrict__ xw16, const float* __restrict__ dinv,
        const float* __restrict__ hprev,
        const float* __restrict__ bcz, const float* __restrict__ bcr, const float* __restrict__ bch,
        const float* __restrict__ Wlz, const float* __restrict__ blz,
        const float* __restrict__ Wlr, const float* __restrict__ blr,
        const float* __restrict__ Wlh, const float* __restrict__ blh,
        const float* __restrict__ Whead, const float* __restrict__ bhead,
        float* __restrict__ y, float* __restrict__ hnew) {
    __shared__ float WzT[64 * 32], WrT[64 * 32], WhT[64 * 32];  // WT[k*32+j] = Wl[j*64+k]
    __shared__ float czs[16][32], crs[16][32], chs[16][32], hps[16][32], rhs[16][32];
    __shared__ uint2 rw[16][32];   // staged (row, wt*dinv[row]) per group
    int tid = threadIdx.x;
    for (int e2 = tid; e2 < 2048; e2 += 512) {
        int jj = e2 >> 6, k = e2 & 63;
        WzT[k * 32 + jj] = Wlz[e2];
        WrT[k * 32 + jj] = Wlr[e2];
        WhT[k * 32 + jj] = Wlh[e2];
    }
    int s = tid >> 5, j = tid & 31;
    int i = blockIdx.x * 16 + s;
    int beg = i * CAP, c = cnt[i], end = beg + c;

    float cz = 0.f, cr = 0.f, ch = 0.f;
    for (int base = beg; base < end; base += 32) {
        int e = base + j;
        if (e < end) {
            uint v = erecp[e];                    // coalesced per group
            int row = (int)(v & 0x1FFFFu);
            float w = __uint_as_float((v >> 17) << 16);
            uint2 q; q.x = (uint)row; q.y = __float_as_uint(w * dinv[row]);
            rw[s][j] = q;                         // L2-resident 400KB dinv gather
        }
        int mm = end - base; if (mm > 32) mm = 32;
        // Same-group LDS RAW (in-order DS within a wave); uniform-address reads
        // broadcast conflict-free (2-way across wave halves is free per m136).
        int t = 0;
        for (; t + 4 <= mm; t += 4) {
            uint2 q0 = rw[s][t], q1 = rw[s][t + 1], q2 = rw[s][t + 2], q3 = rw[s][t + 3];
            const ushort* p0 = xw16 + (long long)q0.x * 96;
            const ushort* p1 = xw16 + (long long)q1.x * 96;
            const ushort* p2 = xw16 + (long long)q2.x * 96;
            const ushort* p3 = xw16 + (long long)q3.x * 96;
            uint a0 = *(const uint*)(p0 + 2 * j);
            uint a1 = *(const uint*)(p1 + 2 * j);
            uint a2 = *(const uint*)(p2 + 2 * j);
            uint a3 = *(const uint*)(p3 + 2 * j);
            ushort h0 = p0[64 + j], h1 = p1[64 + j], h2 = p2[64 + j], h3 = p3[64 + j];
            float w0 = __uint_as_float(q0.y), w1 = __uint_as_float(q1.y);
            float w2 = __uint_as_float(q2.y), w3 = __uint_as_float(q3.y);
            cz = fmaf(w0, __uint_as_float(a0 << 16), cz);
            cr = fmaf(w0, __uint_as_float(a0 & 0xFFFF0000u), cr);
            ch = fmaf(w0, bf2f(h0), ch);
            cz = fmaf(w1, __uint_as_float(a1 << 16), cz);
            cr = fmaf(w1, __uint_as_float(a1 & 0xFFFF0000u), cr);
            ch = fmaf(w1, bf2f(h1), ch);
            cz = fmaf(w2, __uint_as_float(a2 << 16), cz);
            cr = fmaf(w2, __uint_as_float(a2 & 0xFFFF0000u), cr);
            ch = fmaf(w2, bf2f(h2), ch);
            cz = fmaf(w3, __uint_as_float(a3 << 16), cz);
            cr = fmaf(w3, __uint_as_float(a3 & 0xFFFF0000u), cr);
            ch = fmaf(w3, bf2f(h3), ch);
        }
        for (; t < mm; t++) {
            uint2 q = rw[s][t];
            const ushort* xr = xw16 + (long long)q.x * 96;
            uint zr = *(const uint*)(xr + 2 * j);
            float fh = bf2f(xr[64 + j]);
            float w = __uint_as_float(q.y);
            cz = fmaf(w, __uint_as_float(zr << 16), cz);
            cr = fmaf(w, __uint_as_float(zr & 0xFFFF0000u), cr);
            ch = fmaf(w, fh, ch);
        }
    }
    // apply dinv[col] factor; self-loop (norm = dinv^2) + bias
    float di = dinv[i], sl = di * di;
    const ushort* xi = xw16 + (long long)i * 96;
    uint zri = *(const uint*)(xi + 2 * j);
    czs[s][j] = fmaf(sl, __uint_as_float(zri << 16),         di * cz) + bcz[j];
    crs[s][j] = fmaf(sl, __uint_as_float(zri & 0xFFFF0000u), di * cr) + bcr[j];
    chs[s][j] = fmaf(sl, bf2f(xi[64 + j]),                   di * ch) + bch[j];
    float hp = hprev[(long long)i * HD + j];
    hps[s][j] = hp;
    __syncthreads();

    float az = blz[j], arv = blr[j];
#pragma unroll
    for (int k = 0; k < 32; k++) {
        az  = fmaf(WzT[k * 32 + j], czs[s][k], az);
        arv = fmaf(WrT[k * 32 + j], crs[s][k], arv);
    }
#pragma unroll
    for (int k = 0; k < 32; k++) {
        float v = hps[s][k];
        az  = fmaf(WzT[(k + 32) * 32 + j], v, az);
        arv = fmaf(WrT[(k + 32) * 32 + j], v, arv);
    }
    float Z = 1.f / (1.f + __expf(-az));
    float R = 1.f / (1.f + __expf(-arv));
    rhs[s][j] = hp * R;
    __syncthreads();

    float ah = blh[j];
#pragma unroll
    for (int k = 0; k < 32; k++) ah = fmaf(WhT[k * 32 + j], chs[s][k], ah);
#pragma unroll
    for (int k = 0; k < 32; k++) ah = fmaf(WhT[(k + 32) * 32 + j], rhs[s][k], ah);
    float Ht = tanhf(ah);
    float hn = Z * hp + (1.f - Z) * Ht;
    float yv = fmaxf(hn, 0.f) * Whead[j];
#pragma unroll
    for (int m = 16; m; m >>= 1) yv += __shfl_xor(yv, m, 32);
    hnew[(long long)i * HD + j] = hn;
    if (j == 0) y[i] = yv + bhead[0];
}

extern "C" void kernel_launch(void* const* d_in, const int* in_sizes, int n_in,
                              void* d_out, int out_size, void* d_ws, size_t ws_size,
                              hipStream_t stream) {
    const float* x     = (const float*)d_in[0];
    const int*   ei    = (const int*)d_in[1];
    const float* wt    = (const float*)d_in[2];
    const float* hprev = (const float*)d_in[3];
    const float* Wcz = (const float*)d_in[4],  *bcz = (const float*)d_in[5];
    const float* Wlz = (const float*)d_in[6],  *blz = (const float*)d_in[7];
    const float* Wcr = (const float*)d_in[8],  *bcr = (const float*)d_in[9];
    const float* Wlr = (const float*)d_in[10], *blr = (const float*)d_in[11];
    const float* Wch = (const float*)d_in[12], *bch = (const float*)d_in[13];
    const float* Wlh = (const float*)d_in[14], *blh = (const float*)d_in[15];
    const float* Whead = (const float*)d_in[16], *bhead = (const float*)d_in[17];

    float* out_y = (float*)d_out;            // [N]
    float* out_h = (float*)d_out + NN;       // [N,32]

    float* ws = (float*)d_ws;
    float*  dinv   = ws;                               // NN f32      (0.4MB)
    int*    cnt    = (int*)(ws + NN);                  // NN int      (0.4MB)
    int*    flag   = (int*)(ws + 2LL * NN);            // 1 int
    ushort* xw16   = (ushort*)(ws + 3LL * NN);         // 96*NN ushort (19.2MB)
    uint*   erecp  = (uint*)(ws + 51LL * NN);          // NN*CAP uint  (32MB)

    detect_kernel<<<1, 64, 0, stream>>>((const uint*)ei, flag);
    init_kernel<<<NB, 256, 0, stream>>>(cnt);
    edge_bucket_kernel<<<(EE + 255) / 256, 256, 0, stream>>>(ei, wt, cnt, erecp, flag);
    gemm_xw_kernel<<<(NN + 127) / 128, 256, 0, stream>>>(x, Wcz, Wcr, Wch, xw16);
    degsum_kernel<<<NN / 8, 256, 0, stream>>>(erecp, cnt, dinv);
    agg_gate_kernel<<<NN / 16, 512, 0, stream>>>(
        erecp, cnt, xw16, dinv, hprev, bcz, bcr, bch,
        Wlz, blz, Wlr, blr, Wlh, blh, Whead, bhead, out_y, out_h);
}

// Round 7
// 480.167 us; speedup vs baseline: 3.1376x; 1.1576x over previous
//
#include <hip/hip_runtime.h>

#define NN 100000
#define FIN 128
#define HD 32
#define EE 3200000
#define NBUK 391            // coarse buckets of 256 nodes: ceil(NN/256)
#define EPB 16384           // edges per binning block
#define NBLK ((EE + EPB - 1) / EPB)   // 196

typedef unsigned int uint;
typedef unsigned short ushort;

__device__ __forceinline__ ushort f2bf(float f) {
    uint b = __float_as_uint(f);
    return (ushort)((b + 0x7FFFu + ((b >> 16) & 1u)) >> 16);
}
__device__ __forceinline__ float bf2f(ushort u) {
    return __uint_as_float(((uint)u) << 16);
}

// ---------------- dtype detect: edge_index int32 vs int64 ----------------
__global__ void detect_kernel(const uint* __restrict__ ei32, int* __restrict__ flag) {
    int t = threadIdx.x;  // single wave
    uint v = 0;
#pragma unroll
    for (int r = 0; r < 4; r++) v |= ei32[2 * (t + 64 * r) + 1];
    unsigned long long nz = __ballot(v != 0u);
    if (t == 0) *flag = (nz == 0ULL) ? 1 : 0;  // 1 => int64
}

// values < 2^31 and non-negative: for int64, low dword suffices
__device__ __forceinline__ int load_idx32(const int* __restrict__ ei, long long pos, int is64) {
    return is64 ? ei[pos * 2] : ei[pos];
}

// ---------------- passA: coarse histogram (LDS atomics only) ----------------
__global__ __launch_bounds__(256) void passA_hist(const int* __restrict__ ei,
                                                  int* __restrict__ blockhist,
                                                  const int* __restrict__ flag) {
    __shared__ int hist[NBUK];
    int tid = threadIdx.x, blk = blockIdx.x;
    for (int b = tid; b < NBUK; b += 256) hist[b] = 0;
    __syncthreads();
    int is64 = *flag;
    int e0 = blk * EPB, e1 = e0 + EPB; if (e1 > EE) e1 = EE;
    for (int e = e0 + tid; e < e1; e += 256) {
        int col = load_idx32(ei, (long long)EE + e, is64);
        atomicAdd(&hist[col >> 8], 1);
    }
    __syncthreads();
    for (int b = tid; b < NBUK; b += 256) blockhist[blk * NBUK + b] = hist[b];
}

// ---------------- per-bucket exclusive scan over chunks ----------------
__global__ void scan_bucket(const int* __restrict__ blockhist, int* __restrict__ off_local,
                            int* __restrict__ total) {
    int b = blockIdx.x;          // bucket
    int l = threadIdx.x;         // 0..63 (one wave)
    int run = 0;
    for (int c = 0; c < NBLK; c += 64) {
        int blk = c + l;
        int v = (blk < NBLK) ? blockhist[blk * NBUK + b] : 0;
        int incl = v;
#pragma unroll
        for (int d = 1; d < 64; d <<= 1) {
            int t = __shfl_up(incl, d, 64);
            if (l >= d) incl += t;
        }
        if (blk < NBLK) off_local[blk * NBUK + b] = run + (incl - v);
        run += __shfl(incl, 63, 64);
    }
    if (l == 0) total[b] = run;
}

__global__ void scan_total(const int* __restrict__ total, int* __restrict__ bstart) {
    __shared__ int sd[512];
    int t = threadIdx.x;
    int v = (t < NBUK) ? total[t] : 0;
    sd[t] = v;
    __syncthreads();
    for (int off = 1; off < 512; off <<= 1) {
        int x = (t >= off) ? sd[t - off] : 0;
        __syncthreads();
        sd[t] += x;
        __syncthreads();
    }
    if (t < NBUK) bstart[t] = sd[t] - v;
    if (t == NBUK - 1) bstart[NBUK] = sd[t];
}

// ---------------- passC: coarse scatter via LDS cursors (no global atomics) ----
// rec = {row17|bf15(wt)<<17, col&255}; (block,bucket) segments are contiguous.
__global__ __launch_bounds__(256) void passC_scatter(const int* __restrict__ ei,
                                                     const float* __restrict__ wt,
                                                     const int* __restrict__ bstart,
                                                     const int* __restrict__ off_local,
                                                     uint2* __restrict__ erec2,
                                                     const int* __restrict__ flag) {
    __shared__ int cur[NBUK];
    int tid = threadIdx.x, blk = blockIdx.x;
    for (int b = tid; b < NBUK; b += 256) cur[b] = bstart[b] + off_local[blk * NBUK + b];
    __syncthreads();
    int is64 = *flag;
    int e0 = blk * EPB, e1 = e0 + EPB; if (e1 > EE) e1 = EE;
    for (int e = e0 + tid; e < e1; e += 256) {
        int row = load_idx32(ei, e, is64);
        int col = load_idx32(ei, (long long)EE + e, is64);
        uint nb = __float_as_uint(wt[e]);
        uint enc = ((nb + 0x8000u) >> 16) & 0x7FFFu;   // bf16 round, drop sign(=0)
        int pos = atomicAdd(&cur[col >> 8], 1);        // LDS atomic
        uint2 r; r.x = (uint)row | (enc << 17); r.y = (uint)(col & 255);
        erec2[pos] = r;
    }
}

// ---------------- passB: per-bucket fine sort + degree/dinv (fused) ----------
__global__ __launch_bounds__(256) void passB_fine(const uint2* __restrict__ erec2,
                                                  const int* __restrict__ bstart,
                                                  uint* __restrict__ erecF,
                                                  int* __restrict__ estart, int* __restrict__ cnt,
                                                  float* __restrict__ dinv) {
    __shared__ int hist[256];
    __shared__ float wsum[256];
    __shared__ int off[256];
    __shared__ int cur[256];
    __shared__ int sd[256];
    int t = threadIdx.x, b = blockIdx.x;
    hist[t] = 0; wsum[t] = 0.f;
    __syncthreads();
    int e0 = bstart[b], e1 = bstart[b + 1];
    for (int e = e0 + t; e < e1; e += 256) {
        uint2 r = erec2[e];
        int cl = (int)r.y;
        atomicAdd(&hist[cl], 1);
        atomicAdd(&wsum[cl], __uint_as_float((r.x >> 17) << 16));
    }
    __syncthreads();
    int v = hist[t];
    sd[t] = v;
    __syncthreads();
    for (int o = 1; o < 256; o <<= 1) {
        int x = (t >= o) ? sd[t - o] : 0;
        __syncthreads();
        sd[t] += x;
        __syncthreads();
    }
    off[t] = sd[t] - v;
    cur[t] = 0;
    int node = b * 256 + t;
    if (node < NN) {
        estart[node] = e0 + off[t];
        cnt[node] = v;
        dinv[node] = rsqrtf(1.0f + wsum[t]);   // 1 = self-loop weight
    }
    __syncthreads();
    for (int e = e0 + t; e < e1; e += 256) {
        uint2 r = erec2[e];
        int cl = (int)r.y;
        int p = atomicAdd(&cur[cl], 1);        // LDS atomic
        erecF[e0 + off[cl] + p] = r.x;         // dense per-node-sorted
    }
}

// ---------------- xw = x @ [Wc_z | Wc_r | Wc_h]  (f32 VALU, bf16 output) -------
// Output layout per node (96 ushort): [z0,r0, z1,r1, ..., z31,r31, h0..h31]
__global__ __launch_bounds__(256) void gemm_xw_kernel(
        const float* __restrict__ x,
        const float* __restrict__ Wz, const float* __restrict__ Wr, const float* __restrict__ Wh,
        ushort* __restrict__ xw16) {
    __shared__ float Bs[128 * 96];   // Bs[k*96 + c], k GLOBAL (0..127)
    __shared__ float AsT[8 * 128];   // AsT[kk*128 + row], kk local (0..7)
    int tid = threadIdx.x;
    int tx = tid & 31, ty = tid >> 5;
    int rowBase = blockIdx.x * 128;

    for (int e = tid; e < 4096; e += 256) { int k = e >> 5, c = e & 31; Bs[k * 96 + c]      = Wz[e]; }
    for (int e = tid; e < 4096; e += 256) { int k = e >> 5, c = e & 31; Bs[k * 96 + 32 + c] = Wr[e]; }
    for (int e = tid; e < 4096; e += 256) { int k = e >> 5, c = e & 31; Bs[k * 96 + 64 + c] = Wh[e]; }

    float acc0[16], acc1[16], acc2[16];
#pragma unroll
    for (int r = 0; r < 16; r++) { acc0[r] = 0.f; acc1[r] = 0.f; acc2[r] = 0.f; }

    int lr = tid >> 1;
    int lc = (tid & 1) * 4;
    for (int k0 = 0; k0 < 128; k0 += 8) {
        __syncthreads();
        int gr = rowBase + lr;
        float4 a4 = make_float4(0.f, 0.f, 0.f, 0.f);
        if (gr < NN) a4 = *(const float4*)(x + (long long)gr * FIN + k0 + lc);
        AsT[(lc + 0) * 128 + lr] = a4.x;
        AsT[(lc + 1) * 128 + lr] = a4.y;
        AsT[(lc + 2) * 128 + lr] = a4.z;
        AsT[(lc + 3) * 128 + lr] = a4.w;
        __syncthreads();
#pragma unroll
        for (int kk = 0; kk < 8; kk++) {
            float b0 = Bs[(k0 + kk) * 96 + tx];
            float b1 = Bs[(k0 + kk) * 96 + 32 + tx];
            float b2 = Bs[(k0 + kk) * 96 + 64 + tx];
            const float4* ap = (const float4*)(AsT + kk * 128 + ty * 16);
            float4 a0 = ap[0], a1 = ap[1], a2 = ap[2], a3 = ap[3];
            float av[16] = {a0.x,a0.y,a0.z,a0.w, a1.x,a1.y,a1.z,a1.w,
                            a2.x,a2.y,a2.z,a2.w, a3.x,a3.y,a3.z,a3.w};
#pragma unroll
            for (int r = 0; r < 16; r++) {
                acc0[r] = fmaf(av[r], b0, acc0[r]);
                acc1[r] = fmaf(av[r], b1, acc1[r]);
                acc2[r] = fmaf(av[r], b2, acc2[r]);
            }
        }
    }
#pragma unroll
    for (int r = 0; r < 16; r++) {
        int gr = rowBase + ty * 16 + r;
        if (gr < NN) {
            ushort* o = xw16 + (long long)gr * 96;
            uint zr = (uint)f2bf(acc0[r]) | ((uint)f2bf(acc1[r]) << 16);
            *(uint*)(o + 2 * tx) = zr;      // 4B coalesced
            o[64 + tx] = f2bf(acc2[r]);     // 2B
        }
    }
}

// ---------------- fused gather-aggregate + GRU gates + head ----------------
// 32-lane group per node; 16 nodes / 512-thread block; NN = 6250*16 exactly.
// norm = dinv[col] * (wt * dinv[row]); dinv[col] factored out of the sum.
__global__ __launch_bounds__(512) void agg_gate_kernel(
        const uint* __restrict__ erecF, const int* __restrict__ estart, const int* __restrict__ cnt,
        const ushort* __restrict__ xw16, const float* __restrict__ dinv,
        const float* __restrict__ hprev,
        const float* __restrict__ bcz, const float* __restrict__ bcr, const float* __restrict__ bch,
        const float* __restrict__ Wlz, const float* __restrict__ blz,
        const float* __restrict__ Wlr, const float* __restrict__ blr,
        const float* __restrict__ Wlh, const float* __restrict__ blh,
        const float* __restrict__ Whead, const float* __restrict__ bhead,
        float* __restrict__ y, float* __restrict__ hnew) {
    __shared__ float WzT[64 * 32], WrT[64 * 32], WhT[64 * 32];  // WT[k*32+j] = Wl[j*64+k]
    __shared__ float czs[16][32], crs[16][32], chs[16][32], hps[16][32], rhs[16][32];
    __shared__ uint2 rw[16][32];   // staged (row, wt*dinv[row]) per group
    int tid = threadIdx.x;
    for (int e2 = tid; e2 < 2048; e2 += 512) {
        int jj = e2 >> 6, k = e2 & 63;
        WzT[k * 32 + jj] = Wlz[e2];
        WrT[k * 32 + jj] = Wlr[e2];
        WhT[k * 32 + jj] = Wlh[e2];
    }
    int s = tid >> 5, j = tid & 31;
    int i = blockIdx.x * 16 + s;
    int beg = estart[i], c = cnt[i], end = beg + c;

    float cz = 0.f, cr = 0.f, ch = 0.f;
    for (int base = beg; base < end; base += 32) {
        int e = base + j;
        if (e < end) {
            uint v = erecF[e];                    // coalesced per group
            int row = (int)(v & 0x1FFFFu);
            float w = __uint_as_float((v >> 17) << 16);
            uint2 q; q.x = (uint)row; q.y = __float_as_uint(w * dinv[row]);
            rw[s][j] = q;                         // L2-resident 400KB dinv gather
        }
        int mm = end - base; if (mm > 32) mm = 32;
        int t = 0;
        for (; t + 4 <= mm; t += 4) {
            uint2 q0 = rw[s][t], q1 = rw[s][t + 1], q2 = rw[s][t + 2], q3 = rw[s][t + 3];
            const ushort* p0 = xw16 + (long long)q0.x * 96;
            const ushort* p1 = xw16 + (long long)q1.x * 96;
            const ushort* p2 = xw16 + (long long)q2.x * 96;
            const ushort* p3 = xw16 + (long long)q3.x * 96;
            uint a0 = *(const uint*)(p0 + 2 * j);
            uint a1 = *(const uint*)(p1 + 2 * j);
            uint a2 = *(const uint*)(p2 + 2 * j);
            uint a3 = *(const uint*)(p3 + 2 * j);
            ushort h0 = p0[64 + j], h1 = p1[64 + j], h2 = p2[64 + j], h3 = p3[64 + j];
            float w0 = __uint_as_float(q0.y), w1 = __uint_as_float(q1.y);
            float w2 = __uint_as_float(q2.y), w3 = __uint_as_float(q3.y);
            cz = fmaf(w0, __uint_as_float(a0 << 16), cz);
            cr = fmaf(w0, __uint_as_float(a0 & 0xFFFF0000u), cr);
            ch = fmaf(w0, bf2f(h0), ch);
            cz = fmaf(w1, __uint_as_float(a1 << 16), cz);
            cr = fmaf(w1, __uint_as_float(a1 & 0xFFFF0000u), cr);
            ch = fmaf(w1, bf2f(h1), ch);
            cz = fmaf(w2, __uint_as_float(a2 << 16), cz);
            cr = fmaf(w2, __uint_as_float(a2 & 0xFFFF0000u), cr);
            ch = fmaf(w2, bf2f(h2), ch);
            cz = fmaf(w3, __uint_as_float(a3 << 16), cz);
            cr = fmaf(w3, __uint_as_float(a3 & 0xFFFF0000u), cr);
            ch = fmaf(w3, bf2f(h3), ch);
        }
        for (; t < mm; t++) {
            uint2 q = rw[s][t];
            const ushort* xr = xw16 + (long long)q.x * 96;
            uint zr = *(const uint*)(xr + 2 * j);
            float fh = bf2f(xr[64 + j]);
            float w = __uint_as_float(q.y);
            cz = fmaf(w, __uint_as_float(zr << 16), cz);
            cr = fmaf(w, __uint_as_float(zr & 0xFFFF0000u), cr);
            ch = fmaf(w, fh, ch);
        }
    }
    // apply dinv[col] factor; self-loop (norm = dinv^2) + bias
    float di = dinv[i], sl = di * di;
    const ushort* xi = xw16 + (long long)i * 96;
    uint zri = *(const uint*)(xi + 2 * j);
    czs[s][j] = fmaf(sl, __uint_as_float(zri << 16),         di * cz) + bcz[j];
    crs[s][j] = fmaf(sl, __uint_as_float(zri & 0xFFFF0000u), di * cr) + bcr[j];
    chs[s][j] = fmaf(sl, bf2f(xi[64 + j]),                   di * ch) + bch[j];
    float hp = hprev[(long long)i * HD + j];
    hps[s][j] = hp;
    __syncthreads();

    float az = blz[j], arv = blr[j];
#pragma unroll
    for (int k = 0; k < 32; k++) {
        az  = fmaf(WzT[k * 32 + j], czs[s][k], az);
        arv = fmaf(WrT[k * 32 + j], crs[s][k], arv);
    }
#pragma unroll
    for (int k = 0; k < 32; k++) {
        float v = hps[s][k];
        az  = fmaf(WzT[(k + 32) * 32 + j], v, az);
        arv = fmaf(WrT[(k + 32) * 32 + j], v, arv);
    }
    float Z = 1.f / (1.f + __expf(-az));
    float R = 1.f / (1.f + __expf(-arv));
    rhs[s][j] = hp * R;
    __syncthreads();

    float ah = blh[j];
#pragma unroll
    for (int k = 0; k < 32; k++) ah = fmaf(WhT[k * 32 + j], chs[s][k], ah);
#pragma unroll
    for (int k = 0; k < 32; k++) ah = fmaf(WhT[(k + 32) * 32 + j], rhs[s][k], ah);
    float Ht = tanhf(ah);
    float hn = Z * hp + (1.f - Z) * Ht;
    float yv = fmaxf(hn, 0.f) * Whead[j];
#pragma unroll
    for (int m = 16; m; m >>= 1) yv += __shfl_xor(yv, m, 32);
    hnew[(long long)i * HD + j] = hn;
    if (j == 0) y[i] = yv + bhead[0];
}

extern "C" void kernel_launch(void* const* d_in, const int* in_sizes, int n_in,
                              void* d_out, int out_size, void* d_ws, size_t ws_size,
                              hipStream_t stream) {
    const float* x     = (const float*)d_in[0];
    const int*   ei    = (const int*)d_in[1];
    const float* wt    = (const float*)d_in[2];
    const float* hprev = (const float*)d_in[3];
    const float* Wcz = (const float*)d_in[4],  *bcz = (const float*)d_in[5];
    const float* Wlz = (const float*)d_in[6],  *blz = (const float*)d_in[7];
    const float* Wcr = (const float*)d_in[8],  *bcr = (const float*)d_in[9];
    const float* Wlr = (const float*)d_in[10], *blr = (const float*)d_in[11];
    const float* Wch = (const float*)d_in[12], *bch = (const float*)d_in[13];
    const float* Wlh = (const float*)d_in[14], *blh = (const float*)d_in[15];
    const float* Whead = (const float*)d_in[16], *bhead = (const float*)d_in[17];

    float* out_y = (float*)d_out;            // [N]
    float* out_h = (float*)d_out + NN;       // [N,32]

    float* ws = (float*)d_ws;
    float* dinv      = ws;                                   // NN f32
    int*   estart    = (int*)(ws + NN);                      // NN
    int*   cnt       = (int*)(ws + 2LL * NN);                // NN
    int*   bstart    = (int*)(ws + 3LL * NN);                // NBUK+1 (pad 512)
    int*   total     = (int*)(ws + 3LL * NN + 512);          // NBUK (pad 512)
    int*   blockhist = (int*)(ws + 3LL * NN + 1024);         // NBLK*NBUK = 76636 (pad 80000)
    int*   off_local = (int*)(ws + 3LL * NN + 81024);        // 76636 (pad 80000)
    int*   flag      = (int*)(ws + 3LL * NN + 161024);       // 1 (pad 32)
    ushort* xw16     = (ushort*)(ws + 3LL * NN + 161056);    // 96*NN ushort (48NN floats)
    uint2*  erec2    = (uint2*)(ws + 51LL * NN + 161056);    // EE uint2 (8B-aligned: offset even)
    uint*   erecF    = (uint*)(ws + 51LL * NN + 161056 + 2LL * EE);  // EE uint

    detect_kernel<<<1, 64, 0, stream>>>((const uint*)ei, flag);
    passA_hist<<<NBLK, 256, 0, stream>>>(ei, blockhist, flag);
    scan_bucket<<<NBUK, 64, 0, stream>>>(blockhist, off_local, total);
    scan_total<<<1, 512, 0, stream>>>(total, bstart);
    passC_scatter<<<NBLK, 256, 0, stream>>>(ei, wt, bstart, off_local, erec2, flag);
    passB_fine<<<NBUK, 256, 0, stream>>>(erec2, bstart, erecF, estart, cnt, dinv);
    gemm_xw_kernel<<<(NN + 127) / 128, 256, 0, stream>>>(x, Wcz, Wcr, Wch, xw16);
    agg_gate_kernel<<<NN / 16, 512, 0, stream>>>(
        erecF, estart, cnt, xw16, dinv, hprev, bcz, bcr, bch,
        Wlz, blz, Wlr, blr, Wlh, blh, Whead, bhead, out_y, out_h);
}

// Round 8
// 456.358 us; speedup vs baseline: 3.3012x; 1.0522x over previous
//
#include <hip/hip_runtime.h>

#define NN 100000
#define FIN 128
#define HD 32
#define EE 3200000
#define NBUK 391            // coarse buckets of 256 nodes
#define EPB 6144            // edges per binning chunk (LDS-sort fits in 64KB)
#define NBLK ((EE + EPB - 1) / EPB)   // 521

typedef unsigned int uint;
typedef unsigned short ushort;

__device__ __forceinline__ ushort f2bf(float f) {
    uint b = __float_as_uint(f);
    return (ushort)((b + 0x7FFFu + ((b >> 16) & 1u)) >> 16);
}
__device__ __forceinline__ float bf2f(ushort u) {
    return __uint_as_float(((uint)u) << 16);
}

// ---------------- dtype detect: edge_index int32 vs int64 ----------------
__global__ void detect_kernel(const uint* __restrict__ ei32, int* __restrict__ flag) {
    int t = threadIdx.x;  // single wave
    uint v = 0;
#pragma unroll
    for (int r = 0; r < 4; r++) v |= ei32[2 * (t + 64 * r) + 1];
    unsigned long long nz = __ballot(v != 0u);
    if (t == 0) *flag = (nz == 0ULL) ? 1 : 0;  // 1 => int64
}

// values < 2^31 and non-negative: for int64, low dword suffices
__device__ __forceinline__ int load_idx32(const int* __restrict__ ei, long long pos, int is64) {
    return is64 ? ei[pos * 2] : ei[pos];
}

// ---------------- passA: coarse histogram (LDS atomics only) ----------------
__global__ __launch_bounds__(256) void passA_hist(const int* __restrict__ ei,
                                                  int* __restrict__ blockhist,
                                                  const int* __restrict__ flag) {
    __shared__ int hist[NBUK];
    int tid = threadIdx.x, blk = blockIdx.x;
    for (int b = tid; b < NBUK; b += 256) hist[b] = 0;
    __syncthreads();
    int is64 = *flag;
    int e0 = blk * EPB, e1 = e0 + EPB; if (e1 > EE) e1 = EE;
    for (int e = e0 + tid; e < e1; e += 256) {
        int col = load_idx32(ei, (long long)EE + e, is64);
        atomicAdd(&hist[col >> 8], 1);
    }
    __syncthreads();
    for (int b = tid; b < NBUK; b += 256) blockhist[blk * NBUK + b] = hist[b];
}

// ---------------- per-bucket exclusive scan over chunks ----------------
__global__ void scan_bucket(const int* __restrict__ blockhist, int* __restrict__ off_local,
                            int* __restrict__ total) {
    int b = blockIdx.x;          // bucket
    int l = threadIdx.x;         // 0..63 (one wave)
    int run = 0;
    for (int c = 0; c < NBLK; c += 64) {
        int blk = c + l;
        int v = (blk < NBLK) ? blockhist[blk * NBUK + b] : 0;
        int incl = v;
#pragma unroll
        for (int d = 1; d < 64; d <<= 1) {
            int t = __shfl_up(incl, d, 64);
            if (l >= d) incl += t;
        }
        if (blk < NBLK) off_local[blk * NBUK + b] = run + (incl - v);
        run += __shfl(incl, 63, 64);
    }
    if (l == 0) total[b] = run;
}

__global__ void scan_total(const int* __restrict__ total, int* __restrict__ bstart) {
    __shared__ int sd[512];
    int t = threadIdx.x;
    int v = (t < NBUK) ? total[t] : 0;
    sd[t] = v;
    __syncthreads();
    for (int off = 1; off < 512; off <<= 1) {
        int x = (t >= off) ? sd[t - off] : 0;
        __syncthreads();
        sd[t] += x;
        __syncthreads();
    }
    if (t < NBUK) bstart[t] = sd[t] - v;
    if (t == NBUK - 1) bstart[NBUK] = sd[t];
}

// ---------------- sortC: LDS-sorted chunk scatter (coalesced writes) --------
// Records placed bucket-sorted in LDS, then streamed out contiguously.
// rec = {row17 | bf15(wt)<<17, col32}
__global__ __launch_bounds__(256) void sortC_kernel(const int* __restrict__ ei,
                                                    const float* __restrict__ wt,
                                                    const int* __restrict__ bstart,
                                                    const int* __restrict__ off_local,
                                                    const int* __restrict__ blockhist,
                                                    uint2* __restrict__ erec2,
                                                    const int* __restrict__ flag) {
    __shared__ uint2 lrec[EPB];      // 49152 B
    __shared__ int lstart[NBUK];
    __shared__ int lcur[NBUK];
    int tid = threadIdx.x, blk = blockIdx.x;
    if (tid < 64) {                  // wave 0: exclusive scan of this chunk's hist
        int run = 0;
        for (int c = 0; c < NBUK; c += 64) {
            int b = c + tid;
            int v = (b < NBUK) ? blockhist[blk * NBUK + b] : 0;
            int incl = v;
#pragma unroll
            for (int d = 1; d < 64; d <<= 1) {
                int t2 = __shfl_up(incl, d, 64);
                if (tid >= d) incl += t2;
            }
            if (b < NBUK) { lstart[b] = run + incl - v; lcur[b] = run + incl - v; }
            run += __shfl(incl, 63, 64);
        }
    }
    __syncthreads();
    int is64 = *flag;
    int e0 = blk * EPB, e1 = e0 + EPB; if (e1 > EE) e1 = EE;
    for (int e = e0 + tid; e < e1; e += 256) {
        int row = load_idx32(ei, e, is64);
        int col = load_idx32(ei, (long long)EE + e, is64);
        uint nb = __float_as_uint(wt[e]);
        uint enc = ((nb + 0x8000u) >> 16) & 0x7FFFu;   // bf16 round, drop sign(=0)
        int pos = atomicAdd(&lcur[col >> 8], 1);       // LDS atomic
        uint2 r; r.x = (uint)row | (enc << 17); r.y = (uint)col;
        lrec[pos] = r;
    }
    __syncthreads();
    int m = e1 - e0;
    for (int slot = tid; slot < m; slot += 256) {
        uint2 r = lrec[slot];
        int b = (int)(r.y >> 8);
        int gpos = bstart[b] + off_local[blk * NBUK + b] + (slot - lstart[b]);
        erec2[gpos] = r;             // contiguous within each bucket segment
    }
}

// ---------------- passB: per-bucket fine sort + degree/dinv (fused) ----------
__global__ __launch_bounds__(256) void passB_fine(const uint2* __restrict__ erec2,
                                                  const int* __restrict__ bstart,
                                                  uint* __restrict__ erecF,
                                                  int* __restrict__ estart, int* __restrict__ cnt,
                                                  float* __restrict__ dinv) {
    __shared__ int hist[256];
    __shared__ float wsum[256];
    __shared__ int off[256];
    __shared__ int cur[256];
    __shared__ int sd[256];
    int t = threadIdx.x, b = blockIdx.x;
    hist[t] = 0; wsum[t] = 0.f;
    __syncthreads();
    int e0 = bstart[b], e1 = bstart[b + 1];
    for (int e = e0 + t; e < e1; e += 256) {
        uint2 r = erec2[e];
        int cl = (int)(r.y & 255u);
        atomicAdd(&hist[cl], 1);
        atomicAdd(&wsum[cl], __uint_as_float((r.x >> 17) << 16));
    }
    __syncthreads();
    int v = hist[t];
    sd[t] = v;
    __syncthreads();
    for (int o = 1; o < 256; o <<= 1) {
        int x = (t >= o) ? sd[t - o] : 0;
        __syncthreads();
        sd[t] += x;
        __syncthreads();
    }
    off[t] = sd[t] - v;
    cur[t] = 0;
    int node = b * 256 + t;
    if (node < NN) {
        estart[node] = e0 + off[t];
        cnt[node] = v;
        dinv[node] = rsqrtf(1.0f + wsum[t]);   // 1 = self-loop weight
    }
    __syncthreads();
    for (int e = e0 + t; e < e1; e += 256) {
        uint2 r = erec2[e];
        int cl = (int)(r.y & 255u);
        int p = atomicAdd(&cur[cl], 1);        // LDS atomic
        erecF[e0 + off[cl] + p] = r.x;         // dense per-node-sorted (hot 32KB window)
    }
}

// ---------------- fixup: fold dinv[row] into record weight ----------------
// Removes the dependent dinv gather + fmul from agg_gate's staging path.
__global__ void fixup_kernel(uint* __restrict__ erecF, const float* __restrict__ dinv) {
    int e = blockIdx.x * blockDim.x + threadIdx.x;
    if (e >= EE) return;
    uint v = erecF[e];
    int row = (int)(v & 0x1FFFFu);
    float w = __uint_as_float((v >> 17) << 16);
    float wd = w * dinv[row];                  // < 1 always, sign 0
    uint nb = __float_as_uint(wd);
    uint enc = ((nb + 0x8000u) >> 16) & 0x7FFFu;
    erecF[e] = (uint)row | (enc << 17);
}

// ---------------- xw = x @ [Wc_z | Wc_r | Wc_h]  (f32 VALU, bf16 output) -------
// Output layout per node (96 ushort): [z0,r0, z1,r1, ..., z31,r31, h0..h31]
__global__ __launch_bounds__(256) void gemm_xw_kernel(
        const float* __restrict__ x,
        const float* __restrict__ Wz, const float* __restrict__ Wr, const float* __restrict__ Wh,
        ushort* __restrict__ xw16) {
    __shared__ float Bs[128 * 96];   // Bs[k*96 + c], k GLOBAL (0..127)
    __shared__ float AsT[8 * 128];   // AsT[kk*128 + row], kk local (0..7)
    int tid = threadIdx.x;
    int tx = tid & 31, ty = tid >> 5;
    int rowBase = blockIdx.x * 128;

    for (int e = tid; e < 4096; e += 256) { int k = e >> 5, c = e & 31; Bs[k * 96 + c]      = Wz[e]; }
    for (int e = tid; e < 4096; e += 256) { int k = e >> 5, c = e & 31; Bs[k * 96 + 32 + c] = Wr[e]; }
    for (int e = tid; e < 4096; e += 256) { int k = e >> 5, c = e & 31; Bs[k * 96 + 64 + c] = Wh[e]; }

    float acc0[16], acc1[16], acc2[16];
#pragma unroll
    for (int r = 0; r < 16; r++) { acc0[r] = 0.f; acc1[r] = 0.f; acc2[r] = 0.f; }

    int lr = tid >> 1;
    int lc = (tid & 1) * 4;
    for (int k0 = 0; k0 < 128; k0 += 8) {
        __syncthreads();
        int gr = rowBase + lr;
        float4 a4 = make_float4(0.f, 0.f, 0.f, 0.f);
        if (gr < NN) a4 = *(const float4*)(x + (long long)gr * FIN + k0 + lc);
        AsT[(lc + 0) * 128 + lr] = a4.x;
        AsT[(lc + 1) * 128 + lr] = a4.y;
        AsT[(lc + 2) * 128 + lr] = a4.z;
        AsT[(lc + 3) * 128 + lr] = a4.w;
        __syncthreads();
#pragma unroll
        for (int kk = 0; kk < 8; kk++) {
            float b0 = Bs[(k0 + kk) * 96 + tx];
            float b1 = Bs[(k0 + kk) * 96 + 32 + tx];
            float b2 = Bs[(k0 + kk) * 96 + 64 + tx];
            const float4* ap = (const float4*)(AsT + kk * 128 + ty * 16);
            float4 a0 = ap[0], a1 = ap[1], a2 = ap[2], a3 = ap[3];
            float av[16] = {a0.x,a0.y,a0.z,a0.w, a1.x,a1.y,a1.z,a1.w,
                            a2.x,a2.y,a2.z,a2.w, a3.x,a3.y,a3.z,a3.w};
#pragma unroll
            for (int r = 0; r < 16; r++) {
                acc0[r] = fmaf(av[r], b0, acc0[r]);
                acc1[r] = fmaf(av[r], b1, acc1[r]);
                acc2[r] = fmaf(av[r], b2, acc2[r]);
            }
        }
    }
#pragma unroll
    for (int r = 0; r < 16; r++) {
        int gr = rowBase + ty * 16 + r;
        if (gr < NN) {
            ushort* o = xw16 + (long long)gr * 96;
            uint zr = (uint)f2bf(acc0[r]) | ((uint)f2bf(acc1[r]) << 16);
            *(uint*)(o + 2 * tx) = zr;      // 4B coalesced
            o[64 + tx] = f2bf(acc2[r]);     // 2B
        }
    }
}

// ---------------- fused gather-aggregate + GRU gates + head ----------------
// 32-lane group per node; 16 nodes / 512-thread block; NN = 6250*16 exactly.
// Record weight already includes dinv[row] (fixup_kernel); dinv[col] applied once.
// Next batch's records prefetched during current batch's compute.
__global__ __launch_bounds__(512) void agg_gate_kernel(
        const uint* __restrict__ erecF, const int* __restrict__ estart, const int* __restrict__ cnt,
        const ushort* __restrict__ xw16, const float* __restrict__ dinv,
        const float* __restrict__ hprev,
        const float* __restrict__ bcz, const float* __restrict__ bcr, const float* __restrict__ bch,
        const float* __restrict__ Wlz, const float* __restrict__ blz,
        const float* __restrict__ Wlr, const float* __restrict__ blr,
        const float* __restrict__ Wlh, const float* __restrict__ blh,
        const float* __restrict__ Whead, const float* __restrict__ bhead,
        float* __restrict__ y, float* __restrict__ hnew) {
    __shared__ float WzT[64 * 32], WrT[64 * 32], WhT[64 * 32];  // WT[k*32+j] = Wl[j*64+k]
    __shared__ float czs[16][32], crs[16][32], chs[16][32], hps[16][32], rhs[16][32];
    __shared__ uint rwsh[16][32];   // staged records per group
    int tid = threadIdx.x;
    for (int e2 = tid; e2 < 2048; e2 += 512) {
        int jj = e2 >> 6, k = e2 & 63;
        WzT[k * 32 + jj] = Wlz[e2];
        WrT[k * 32 + jj] = Wlr[e2];
        WhT[k * 32 + jj] = Wlh[e2];
    }
    int s = tid >> 5, j = tid & 31;
    int i = blockIdx.x * 16 + s;
    int beg = estart[i], c = cnt[i], end = beg + c;

    float cz = 0.f, cr = 0.f, ch = 0.f;
    int e = beg + j;
    uint vcur = (e < end) ? erecF[e] : 0u;      // batch 0
    for (int base = beg; base < end; base += 32) {
        rwsh[s][j] = vcur;                      // in-order DS within wave: safe
        int en = base + 32 + j;
        uint vnext = (en < end) ? erecF[en] : 0u;   // prefetch next batch
        int mm = end - base; if (mm > 32) mm = 32;
        int t = 0;
        for (; t + 4 <= mm; t += 4) {
            uint v0 = rwsh[s][t], v1 = rwsh[s][t + 1], v2 = rwsh[s][t + 2], v3 = rwsh[s][t + 3];
            const ushort* p0 = xw16 + (long long)(v0 & 0x1FFFFu) * 96;
            const ushort* p1 = xw16 + (long long)(v1 & 0x1FFFFu) * 96;
            const ushort* p2 = xw16 + (long long)(v2 & 0x1FFFFu) * 96;
            const ushort* p3 = xw16 + (long long)(v3 & 0x1FFFFu) * 96;
            uint a0 = *(const uint*)(p0 + 2 * j);
            uint a1 = *(const uint*)(p1 + 2 * j);
            uint a2 = *(const uint*)(p2 + 2 * j);
            uint a3 = *(const uint*)(p3 + 2 * j);
            ushort h0 = p0[64 + j], h1 = p1[64 + j], h2 = p2[64 + j], h3 = p3[64 + j];
            float w0 = __uint_as_float((v0 >> 17) << 16);
            float w1 = __uint_as_float((v1 >> 17) << 16);
            float w2 = __uint_as_float((v2 >> 17) << 16);
            float w3 = __uint_as_float((v3 >> 17) << 16);
            cz = fmaf(w0, __uint_as_float(a0 << 16), cz);
            cr = fmaf(w0, __uint_as_float(a0 & 0xFFFF0000u), cr);
            ch = fmaf(w0, bf2f(h0), ch);
            cz = fmaf(w1, __uint_as_float(a1 << 16), cz);
            cr = fmaf(w1, __uint_as_float(a1 & 0xFFFF0000u), cr);
            ch = fmaf(w1, bf2f(h1), ch);
            cz = fmaf(w2, __uint_as_float(a2 << 16), cz);
            cr = fmaf(w2, __uint_as_float(a2 & 0xFFFF0000u), cr);
            ch = fmaf(w2, bf2f(h2), ch);
            cz = fmaf(w3, __uint_as_float(a3 << 16), cz);
            cr = fmaf(w3, __uint_as_float(a3 & 0xFFFF0000u), cr);
            ch = fmaf(w3, bf2f(h3), ch);
        }
        for (; t < mm; t++) {
            uint v = rwsh[s][t];
            const ushort* xr = xw16 + (long long)(v & 0x1FFFFu) * 96;
            uint zr = *(const uint*)(xr + 2 * j);
            float fh = bf2f(xr[64 + j]);
            float w = __uint_as_float((v >> 17) << 16);
            cz = fmaf(w, __uint_as_float(zr << 16), cz);
            cr = fmaf(w, __uint_as_float(zr & 0xFFFF0000u), cr);
            ch = fmaf(w, fh, ch);
        }
        vcur = vnext;
    }
    // apply dinv[col] factor; self-loop (norm = dinv^2) + bias
    float di = dinv[i], sl = di * di;
    const ushort* xi = xw16 + (long long)i * 96;
    uint zri = *(const uint*)(xi + 2 * j);
    czs[s][j] = fmaf(sl, __uint_as_float(zri << 16),         di * cz) + bcz[j];
    crs[s][j] = fmaf(sl, __uint_as_float(zri & 0xFFFF0000u), di * cr) + bcr[j];
    chs[s][j] = fmaf(sl, bf2f(xi[64 + j]),                   di * ch) + bch[j];
    float hp = hprev[(long long)i * HD + j];
    hps[s][j] = hp;
    __syncthreads();

    float az = blz[j], arv = blr[j];
#pragma unroll
    for (int k = 0; k < 32; k++) {
        az  = fmaf(WzT[k * 32 + j], czs[s][k], az);
        arv = fmaf(WrT[k * 32 + j], crs[s][k], arv);
    }
#pragma unroll
    for (int k = 0; k < 32; k++) {
        float v = hps[s][k];
        az  = fmaf(WzT[(k + 32) * 32 + j], v, az);
        arv = fmaf(WrT[(k + 32) * 32 + j], v, arv);
    }
    float Z = 1.f / (1.f + __expf(-az));
    float R = 1.f / (1.f + __expf(-arv));
    rhs[s][j] = hp * R;
    __syncthreads();

    float ah = blh[j];
#pragma unroll
    for (int k = 0; k < 32; k++) ah = fmaf(WhT[k * 32 + j], chs[s][k], ah);
#pragma unroll
    for (int k = 0; k < 32; k++) ah = fmaf(WhT[(k + 32) * 32 + j], rhs[s][k], ah);
    float Ht = tanhf(ah);
    float hn = Z * hp + (1.f - Z) * Ht;
    float yv = fmaxf(hn, 0.f) * Whead[j];
#pragma unroll
    for (int m = 16; m; m >>= 1) yv += __shfl_xor(yv, m, 32);
    hnew[(long long)i * HD + j] = hn;
    if (j == 0) y[i] = yv + bhead[0];
}

extern "C" void kernel_launch(void* const* d_in, const int* in_sizes, int n_in,
                              void* d_out, int out_size, void* d_ws, size_t ws_size,
                              hipStream_t stream) {
    const float* x     = (const float*)d_in[0];
    const int*   ei    = (const int*)d_in[1];
    const float* wt    = (const float*)d_in[2];
    const float* hprev = (const float*)d_in[3];
    const float* Wcz = (const float*)d_in[4],  *bcz = (const float*)d_in[5];
    const float* Wlz = (const float*)d_in[6],  *blz = (const float*)d_in[7];
    const float* Wcr = (const float*)d_in[8],  *bcr = (const float*)d_in[9];
    const float* Wlr = (const float*)d_in[10], *blr = (const float*)d_in[11];
    const float* Wch = (const float*)d_in[12], *bch = (const float*)d_in[13];
    const float* Wlh = (const float*)d_in[14], *blh = (const float*)d_in[15];
    const float* Whead = (const float*)d_in[16], *bhead = (const float*)d_in[17];

    float* out_y = (float*)d_out;            // [N]
    float* out_h = (float*)d_out + NN;       // [N,32]

    float* ws = (float*)d_ws;
    float* dinv      = ws;                                   // NN f32
    int*   estart    = (int*)(ws + NN);                      // NN
    int*   cnt       = (int*)(ws + 2LL * NN);                // NN
    int*   bstart    = (int*)(ws + 3LL * NN);                // NBUK+1 (pad 512)
    int*   total     = (int*)(ws + 3LL * NN + 512);          // NBUK (pad 512)
    int*   blockhist = (int*)(ws + 3LL * NN + 1024);         // NBLK*NBUK=203711 (pad 204000)
    int*   off_local = (int*)(ws + 3LL * NN + 205024);       // 203711 (pad 204000)
    int*   flag      = (int*)(ws + 3LL * NN + 409024);       // 1 (pad 32)
    ushort* xw16     = (ushort*)(ws + 3LL * NN + 409056);    // 96*NN ushort (= 48NN f32)
    uint2*  erec2    = (uint2*)(ws + 51LL * NN + 409056);    // EE uint2 (even offset, 8B-aligned)
    uint*   erecF    = (uint*)(ws + 51LL * NN + 409056 + 2LL * EE);  // EE uint

    detect_kernel<<<1, 64, 0, stream>>>((const uint*)ei, flag);
    passA_hist<<<NBLK, 256, 0, stream>>>(ei, blockhist, flag);
    scan_bucket<<<NBUK, 64, 0, stream>>>(blockhist, off_local, total);
    scan_total<<<1, 512, 0, stream>>>(total, bstart);
    sortC_kernel<<<NBLK, 256, 0, stream>>>(ei, wt, bstart, off_local, blockhist, erec2, flag);
    passB_fine<<<NBUK, 256, 0, stream>>>(erec2, bstart, erecF, estart, cnt, dinv);
    gemm_xw_kernel<<<(NN + 127) / 128, 256, 0, stream>>>(x, Wcz, Wcr, Wch, xw16);
    fixup_kernel<<<(EE + 255) / 256, 256, 0, stream>>>(erecF, dinv);
    agg_gate_kernel<<<NN / 16, 512, 0, stream>>>(
        erecF, estart, cnt, xw16, dinv, hprev, bcz, bcr, bch,
        Wlz, blz, Wlr, blr, Wlh, blh, Whead, bhead, out_y, out_h);
}